// Round 1
// baseline (2506.806 us; speedup 1.0000x reference)
//
#include <hip/hip_runtime.h>

// Problem constants (fixed by reference)
constexpr int GN = 100000;   // nodes
constexpr int GE = 1600000;  // edges
constexpr int GD = 64;       // node feature dim
constexpr int GM = 128;      // classifier hidden
constexpr float FN = 100000.0f;
constexpr float BN_EPS = 1e-5f;

// ---------------- CSR build ----------------

__global__ __launch_bounds__(256) void hist_kernel(const int* __restrict__ dst,
                                                   int* __restrict__ deg) {
    for (int i = blockIdx.x * blockDim.x + threadIdx.x; i < GE; i += gridDim.x * blockDim.x)
        atomicAdd(&deg[dst[i]], 1);
}

__global__ __launch_bounds__(1024) void scan_kernel(const int* __restrict__ deg,
                                                    int* __restrict__ off) {
    __shared__ int buf[1024];
    __shared__ int carryS;
    int t = threadIdx.x;
    if (t == 0) { carryS = 0; off[0] = 0; }
    __syncthreads();
    for (int base = 0; base < GN; base += 4096) {
        int i0 = base + t * 4;
        int v0 = (i0 + 0 < GN) ? deg[i0 + 0] : 0;
        int v1 = (i0 + 1 < GN) ? deg[i0 + 1] : 0;
        int v2 = (i0 + 2 < GN) ? deg[i0 + 2] : 0;
        int v3 = (i0 + 3 < GN) ? deg[i0 + 3] : 0;
        int s = v0 + v1 + v2 + v3;
        buf[t] = s;
        __syncthreads();
        for (int o = 1; o < 1024; o <<= 1) {
            int add = (t >= o) ? buf[t - o] : 0;
            __syncthreads();
            buf[t] += add;
            __syncthreads();
        }
        int carry = carryS;
        int pre = carry + buf[t] - s;  // exclusive prefix for this thread's 4 elems
        int e0 = pre + v0; if (i0 + 0 < GN) off[i0 + 1] = e0;
        int e1 = e0  + v1; if (i0 + 1 < GN) off[i0 + 2] = e1;
        int e2 = e1  + v2; if (i0 + 2 < GN) off[i0 + 3] = e2;
        int e3 = e2  + v3; if (i0 + 3 < GN) off[i0 + 4] = e3;
        int tot = buf[1023];
        __syncthreads();
        if (t == 0) carryS = carry + tot;
        __syncthreads();
    }
}

__global__ __launch_bounds__(256) void fill_kernel(const int* __restrict__ dst,
                                                   int* __restrict__ cursor,
                                                   int* __restrict__ eids) {
    for (int i = blockIdx.x * blockDim.x + threadIdx.x; i < GE; i += gridDim.x * blockDim.x) {
        int pos = atomicAdd(&cursor[dst[i]], 1);
        eids[pos] = i;
    }
}

// ---------------- column stats (standalone, for x) ----------------

__global__ __launch_bounds__(256) void col_stats64(const float* __restrict__ in,
                                                   float* __restrict__ sum,
                                                   float* __restrict__ sq) {
    int c = threadIdx.x & 63;
    int lr = threadIdx.x >> 6;  // 0..3
    float s = 0.f, q = 0.f;
    for (int r = blockIdx.x * 4 + lr; r < GN; r += gridDim.x * 4) {
        float v = in[(size_t)r * 64 + c];
        s += v; q += v * v;
    }
    __shared__ float S[256];
    S[threadIdx.x] = s;
    __syncthreads();
    if (threadIdx.x < 64) {
        float a = S[threadIdx.x] + S[threadIdx.x + 64] + S[threadIdx.x + 128] + S[threadIdx.x + 192];
        atomicAdd(&sum[threadIdx.x], a);
    }
    __syncthreads();
    S[threadIdx.x] = q;
    __syncthreads();
    if (threadIdx.x < 64) {
        float a = S[threadIdx.x] + S[threadIdx.x + 64] + S[threadIdx.x + 128] + S[threadIdx.x + 192];
        atomicAdd(&sq[threadIdx.x], a);
    }
}

// ---------------- fused BN(pre) + GINE aggregation ----------------
// One wave per node. BN applied on the fly to every gathered h row (BN is
// per-column elementwise, so gather from raw h and transform).
// z[n][d] = (1+eps)*hi[n][d] + sum_{e: dst=n} relu(hi[src(e)][d] + eattr(e)@We^T[d] + be[d])

__global__ __launch_bounds__(256) void aggregate_kernel(
    const float* __restrict__ h,        // raw input (x or previous h), [N,64]
    const float* __restrict__ sum, const float* __restrict__ sq,   // pre-BN stats
    const float* __restrict__ bnw, const float* __restrict__ bnb,  // bn_pre w,b (this layer)
    int leaky,                           // apply leaky after BN? (layers >0)
    const int* __restrict__ off, const int* __restrict__ eids,
    const int* __restrict__ srcArr, const float* __restrict__ attr,
    const float* __restrict__ Wle,      // edge_lin_w[i], [64][16]
    const float* __restrict__ ble,      // edge_lin_b[i], [64]
    const float* __restrict__ epsArr, int layer,
    float* __restrict__ z) {
    int node = blockIdx.x * 4 + (threadIdx.x >> 6);
    int d = threadIdx.x & 63;
    if (node >= GN) return;

    // per-lane BN coeffs for column d
    float m = sum[d] / FN;
    float var = sq[d] / FN - m * m;
    float cA = rsqrtf(var + BN_EPS) * bnw[d];
    float cB = bnb[d] - m * cA;

    // per-lane edge-linear weight row W[d][0..15]
    const float4* wp = (const float4*)(Wle + d * 16);
    float4 w0 = wp[0], w1 = wp[1], w2 = wp[2], w3 = wp[3];
    float be = ble[d];
    float epsv = 1.0f + epsArr[layer];

    int p = off[node], p1 = off[node + 1];
    float acc = 0.0f;

    int eid = 0, s = 0;
    float4 a0, a1, a2, a3;
    if (p < p1) {
        eid = eids[p];
        s = srcArr[eid];
        const float4* ap = (const float4*)(attr + (size_t)eid * 16);
        a0 = ap[0]; a1 = ap[1]; a2 = ap[2]; a3 = ap[3];
    }
    while (p < p1) {
        int pn = p + 1;
        bool more = pn < p1;
        int s2 = 0;
        float4 b0, b1, b2, b3;
        if (more) {
            int eid2 = eids[pn];
            s2 = srcArr[eid2];
            const float4* bp = (const float4*)(attr + (size_t)eid2 * 16);
            b0 = bp[0]; b1 = bp[1]; b2 = bp[2]; b3 = bp[3];
        }
        float g = h[(size_t)s * 64 + d];
        g = g * cA + cB;                       // fused bn_pre
        if (leaky) g = g > 0.f ? g : 0.01f * g;
        float e = be;
        e += a0.x * w0.x + a0.y * w0.y + a0.z * w0.z + a0.w * w0.w;
        e += a1.x * w1.x + a1.y * w1.y + a1.z * w1.z + a1.w * w1.w;
        e += a2.x * w2.x + a2.y * w2.y + a2.z * w2.z + a2.w * w2.w;
        e += a3.x * w3.x + a3.y * w3.y + a3.z * w3.z + a3.w * w3.w;
        float msg = g + e;
        acc += fmaxf(msg, 0.0f);
        p = pn;
        if (more) { s = s2; a0 = b0; a1 = b1; a2 = b2; a3 = b3; }
    }
    float hv = h[(size_t)node * 64 + d];
    hv = hv * cA + cB;
    if (leaky) hv = hv > 0.f ? hv : 0.01f * hv;
    z[(size_t)node * 64 + d] = epsv * hv + acc;
}

// ---------------- tiled GEMM: dst = f(src) @ W^T + bias [+resid], fused stats ----------------
// src: [N, src_ld] using 64 input cols. W: [outCols][64] row-major (use col tile via blockIdx.y).
// BN_IN: apply batchnorm(statsIn,bnw,bnb) + leaky to src elements while staging.
// statsOut: accumulate column sum/sumsq of the STORED outputs.

template <bool BN_IN>
__global__ __launch_bounds__(256) void gemm64(
    const float* __restrict__ src, int src_ld,
    const float* __restrict__ W, const float* __restrict__ bias,
    float* __restrict__ dst, int dst_ld,
    const float* __restrict__ resid,
    const float* __restrict__ statsInSum, const float* __restrict__ statsInSq,
    const float* __restrict__ bnw, const float* __restrict__ bnb,
    float* __restrict__ statsOutSum, float* __restrict__ statsOutSq) {
    __shared__ float Wl[64][68];
    __shared__ float Zl[64][68];
    __shared__ float cA[64], cB[64];
    int tid = threadIdx.x;
    int r0 = blockIdx.x * 64;
    int c0 = blockIdx.y * 64;

    if (BN_IN) {
        if (tid < 64) {
            float m = statsInSum[tid] / FN;
            float var = statsInSq[tid] / FN - m * m;
            float a = rsqrtf(var + BN_EPS) * bnw[tid];
            cA[tid] = a;
            cB[tid] = bnb[tid] - m * a;
        }
        __syncthreads();
    }

    const float* Wt = W + (size_t)c0 * 64;
#pragma unroll
    for (int j = 0; j < 4; ++j) {
        int idx = tid + j * 256;  // 0..1023
        int row = idx >> 4, c4 = idx & 15;
        float4 v = *(const float4*)(Wt + (size_t)row * 64 + c4 * 4);
        *(float4*)&Wl[row][c4 * 4] = v;
    }
#pragma unroll
    for (int j = 0; j < 4; ++j) {
        int idx = tid + j * 256;
        int row = idx >> 4, c4 = idx & 15;
        int gr = r0 + row;
        float4 v;
        if (gr < GN) v = *(const float4*)(src + (size_t)gr * src_ld + c4 * 4);
        else { v.x = v.y = v.z = v.w = 0.f; }
        if (BN_IN) {
            int c = c4 * 4;
            v.x = v.x * cA[c + 0] + cB[c + 0];
            v.y = v.y * cA[c + 1] + cB[c + 1];
            v.z = v.z * cA[c + 2] + cB[c + 2];
            v.w = v.w * cA[c + 3] + cB[c + 3];
            v.x = v.x > 0.f ? v.x : 0.01f * v.x;
            v.y = v.y > 0.f ? v.y : 0.01f * v.y;
            v.z = v.z > 0.f ? v.z : 0.01f * v.z;
            v.w = v.w > 0.f ? v.w : 0.01f * v.w;
        }
        *(float4*)&Zl[row][c4 * 4] = v;
    }
    __syncthreads();

    int rg = tid >> 4, cg = tid & 15;
    float acc[4][4];
#pragma unroll
    for (int i = 0; i < 4; ++i)
#pragma unroll
        for (int j = 0; j < 4; ++j) acc[i][j] = 0.f;

#pragma unroll
    for (int k4 = 0; k4 < 16; ++k4) {
        float4 zr[4], wc[4];
#pragma unroll
        for (int rr = 0; rr < 4; ++rr) zr[rr] = *(const float4*)&Zl[rg * 4 + rr][k4 * 4];
#pragma unroll
        for (int cc = 0; cc < 4; ++cc) wc[cc] = *(const float4*)&Wl[cg * 4 + cc][k4 * 4];
#pragma unroll
        for (int rr = 0; rr < 4; ++rr)
#pragma unroll
            for (int cc = 0; cc < 4; ++cc)
                acc[rr][cc] += zr[rr].x * wc[cc].x + zr[rr].y * wc[cc].y +
                               zr[rr].z * wc[cc].z + zr[rr].w * wc[cc].w;
    }

    float colS[4] = {0.f, 0.f, 0.f, 0.f};
    float colQ[4] = {0.f, 0.f, 0.f, 0.f};
#pragma unroll
    for (int rr = 0; rr < 4; ++rr) {
        int gr = r0 + rg * 4 + rr;
        if (gr < GN) {
            float o[4];
#pragma unroll
            for (int cc = 0; cc < 4; ++cc) o[cc] = acc[rr][cc] + bias[c0 + cg * 4 + cc];
            if (resid) {
                float4 rv = *(const float4*)(resid + (size_t)gr * dst_ld + c0 + cg * 4);
                o[0] += rv.x; o[1] += rv.y; o[2] += rv.z; o[3] += rv.w;
            }
            float4 ov; ov.x = o[0]; ov.y = o[1]; ov.z = o[2]; ov.w = o[3];
            *(float4*)(dst + (size_t)gr * dst_ld + c0 + cg * 4) = ov;
#pragma unroll
            for (int cc = 0; cc < 4; ++cc) { colS[cc] += o[cc]; colQ[cc] += o[cc] * o[cc]; }
        }
    }

    if (statsOutSum) {
        float* S = &Zl[0][0];  // reuse as [64 cols][16 rowgroups] scratch
        __syncthreads();
#pragma unroll
        for (int cc = 0; cc < 4; ++cc) S[(cg * 4 + cc) * 16 + rg] = colS[cc];
        __syncthreads();
        if (tid < 64) {
            float s = 0.f;
#pragma unroll
            for (int j = 0; j < 16; ++j) s += S[tid * 16 + j];
            atomicAdd(&statsOutSum[c0 + tid], s);
        }
        __syncthreads();
#pragma unroll
        for (int cc = 0; cc < 4; ++cc) S[(cg * 4 + cc) * 16 + rg] = colQ[cc];
        __syncthreads();
        if (tid < 64) {
            float s = 0.f;
#pragma unroll
            for (int j = 0; j < 16; ++j) s += S[tid * 16 + j];
            atomicAdd(&statsOutSq[c0 + tid], s);
        }
    }
}

// ---------------- classifier tail: out[n] = leaky(bn(y1[n,:]))·w2 + b2 ----------------

__global__ __launch_bounds__(256) void cls2_kernel(
    const float* __restrict__ y1,
    const float* __restrict__ sum, const float* __restrict__ sq,
    const float* __restrict__ bnw, const float* __restrict__ bnb,
    const float* __restrict__ w2, const float* __restrict__ b2,
    float* __restrict__ out) {
    int node = blockIdx.x * 4 + (threadIdx.x >> 6);
    int d = threadIdx.x & 63;
    if (node >= GN) return;
    float partial = 0.f;
#pragma unroll
    for (int hh = 0; hh < 2; ++hh) {
        int c = d + hh * 64;
        float m = sum[c] / FN;
        float var = sq[c] / FN - m * m;
        float a = rsqrtf(var + BN_EPS) * bnw[c];
        float v = y1[(size_t)node * 128 + c];
        v = v * a + (bnb[c] - m * a);
        v = v > 0.f ? v : 0.01f * v;
        partial += v * w2[c];
    }
    for (int o = 32; o >= 1; o >>= 1) partial += __shfl_down(partial, o, 64);
    if (d == 0) out[node] = partial + b2[0];
}

// ---------------- launcher ----------------

extern "C" void kernel_launch(void* const* d_in, const int* in_sizes, int n_in,
                              void* d_out, int out_size, void* d_ws, size_t ws_size,
                              hipStream_t stream) {
    (void)in_sizes; (void)n_in; (void)out_size; (void)ws_size;
    const float* x    = (const float*)d_in[0];
    const int*   ei   = (const int*)d_in[1];
    const float* attr = (const float*)d_in[2];
    const float* bnpw = (const float*)d_in[3];
    const float* bnpb = (const float*)d_in[4];
    const float* elw  = (const float*)d_in[5];
    const float* elb  = (const float*)d_in[6];
    const float* l1w  = (const float*)d_in[7];
    const float* l1b  = (const float*)d_in[8];
    const float* bnmw = (const float*)d_in[9];
    const float* bnmb = (const float*)d_in[10];
    const float* l2w  = (const float*)d_in[11];
    const float* l2b  = (const float*)d_in[12];
    const float* epsA = (const float*)d_in[13];
    const float* c1w  = (const float*)d_in[14];
    const float* c1b  = (const float*)d_in[15];
    const float* cbw  = (const float*)d_in[16];
    const float* cbb  = (const float*)d_in[17];
    const float* c2w  = (const float*)d_in[18];
    const float* c2b  = (const float*)d_in[19];
    const int* srcArr = ei;
    const int* dstArr = ei + GE;

    char* base = (char*)d_ws;
    size_t ofs = 0;
    auto alloc = [&](size_t bytes) {
        void* p = base + ofs;
        ofs = (ofs + bytes + 1023) & ~(size_t)1023;
        return p;
    };
    int* off      = (int*)alloc((size_t)(GN + 1) * 4);
    int* cursor   = (int*)alloc((size_t)GN * 4);
    int* eids     = (int*)alloc((size_t)GE * 4);
    float* stPre  = (float*)alloc(128 * 4);  // sum[64] | sq[64]
    float* stMid  = (float*)alloc(128 * 4);
    float* stCls  = (float*)alloc(256 * 4);  // sum[128] | sq[128]
    float* h      = (float*)alloc((size_t)GN * 64 * 4);
    float* z      = (float*)alloc((size_t)GN * 64 * 4);
    float* t      = (float*)alloc((size_t)GN * 64 * 4);
    float* y1     = z;  // z and t are contiguous (each 25,600,000 B, 1024-aligned) -> [N,128]

    // ---- CSR by dst (once; edge_index constant across layers) ----
    hipMemsetAsync(cursor, 0, (size_t)GN * 4, stream);
    hist_kernel<<<2048, 256, 0, stream>>>(dstArr, cursor);
    scan_kernel<<<1, 1024, 0, stream>>>(cursor, off);
    hipMemcpyAsync(cursor, off, (size_t)GN * 4, hipMemcpyDeviceToDevice, stream);
    fill_kernel<<<2048, 256, 0, stream>>>(dstArr, cursor, eids);

    // ---- layer-0 pre-BN stats on x ----
    hipMemsetAsync(stPre, 0, 128 * 4, stream);
    col_stats64<<<512, 256, 0, stream>>>(x, stPre, stPre + 64);

    const float* hsrc = x;
    dim3 g1(1563, 1);
    for (int i = 0; i < 4; ++i) {
        aggregate_kernel<<<25000, 256, 0, stream>>>(
            hsrc, stPre, stPre + 64, bnpw + i * 64, bnpb + i * 64, (i > 0) ? 1 : 0,
            off, eids, srcArr, attr, elw + i * 1024, elb + i * 64, epsA, i, z);
        hipMemsetAsync(stMid, 0, 128 * 4, stream);
        gemm64<false><<<g1, 256, 0, stream>>>(
            z, 64, l1w + i * 4096, l1b + i * 64, t, 64, nullptr,
            nullptr, nullptr, nullptr, nullptr, stMid, stMid + 64);
        hipMemsetAsync(stPre, 0, 128 * 4, stream);
        gemm64<true><<<g1, 256, 0, stream>>>(
            t, 64, l2w + i * 4096, l2b + i * 64, h, 64, (i > 0) ? h : nullptr,
            stMid, stMid + 64, bnmw + i * 64, bnmb + i * 64, stPre, stPre + 64);
        hsrc = h;
    }

    // ---- classifier ----
    hipMemsetAsync(stCls, 0, 256 * 4, stream);
    dim3 gc(1563, 2);
    gemm64<false><<<gc, 256, 0, stream>>>(
        h, 64, c1w, c1b, y1, 128, nullptr,
        nullptr, nullptr, nullptr, nullptr, stCls, stCls + 128);
    cls2_kernel<<<25000, 256, 0, stream>>>(y1, stCls, stCls + 128, cbw, cbb, c2w, c2b,
                                           (float*)d_out);
}

// Round 2
// 2104.150 us; speedup vs baseline: 1.1914x; 1.1914x over previous
//
#include <hip/hip_runtime.h>

// Problem constants (fixed by reference)
constexpr int GN = 100000;   // nodes
constexpr int GE = 1600000;  // edges
constexpr float FN = 100000.0f;
constexpr float BN_EPS = 1e-5f;

// ---------------- CSR build ----------------

__global__ __launch_bounds__(256) void hist_kernel(const int* __restrict__ dst,
                                                   int* __restrict__ deg) {
    for (int i = blockIdx.x * blockDim.x + threadIdx.x; i < GE; i += gridDim.x * blockDim.x)
        atomicAdd(&deg[dst[i]], 1);
}

// hierarchical exclusive scan of deg[0..GN) -> off[0..GN], off[GN]=total
// 98 blocks x 1024 elems each
__global__ __launch_bounds__(256) void bsum_kernel(const int* __restrict__ deg,
                                                   int* __restrict__ bsum) {
    int b = blockIdx.x;
    int i0 = b * 1024 + threadIdx.x * 4;
    int s = 0;
#pragma unroll
    for (int k = 0; k < 4; ++k) {
        int i = i0 + k;
        if (i < GN) s += deg[i];
    }
    for (int o = 32; o >= 1; o >>= 1) s += __shfl_down(s, o, 64);
    __shared__ int ws[4];
    if ((threadIdx.x & 63) == 0) ws[threadIdx.x >> 6] = s;
    __syncthreads();
    if (threadIdx.x == 0) bsum[b] = ws[0] + ws[1] + ws[2] + ws[3];
}

__global__ void bscan_kernel(const int* __restrict__ bsum, int* __restrict__ bbase,
                             int* __restrict__ offEnd, int nb) {
    int t = threadIdx.x;  // 64 threads, 1 wave
    int carry = 0;
    for (int base = 0; base < nb; base += 64) {
        int v = (base + t < nb) ? bsum[base + t] : 0;
        int incl = v;
        for (int o = 1; o < 64; o <<= 1) {
            int u = __shfl_up(incl, o, 64);
            if (t >= o) incl += u;
        }
        if (base + t < nb) bbase[base + t] = carry + incl - v;
        carry += __shfl(incl, 63, 64);
    }
    if (t == 0) offEnd[0] = carry;
}

__global__ __launch_bounds__(256) void bscatter_kernel(const int* __restrict__ deg,
                                                       const int* __restrict__ bbase,
                                                       int* __restrict__ off) {
    int b = blockIdx.x;
    int t = threadIdx.x;
    int i0 = b * 1024 + t * 4;
    int v[4];
    int s = 0;
#pragma unroll
    for (int k = 0; k < 4; ++k) {
        int i = i0 + k;
        v[k] = (i < GN) ? deg[i] : 0;
        s += v[k];
    }
    int incl = s;
    int lane = t & 63;
    for (int o = 1; o < 64; o <<= 1) {
        int u = __shfl_up(incl, o, 64);
        if (lane >= o) incl += u;
    }
    __shared__ int wsum[4];
    if (lane == 63) wsum[t >> 6] = incl;
    __syncthreads();
    int w = t >> 6;
    int wb = 0;
#pragma unroll
    for (int k = 0; k < 4; ++k)
        if (k < w) wb += wsum[k];
    int ex = bbase[b] + wb + incl - s;
#pragma unroll
    for (int k = 0; k < 4; ++k) {
        int i = i0 + k;
        if (i < GN) off[i] = ex;
        ex += v[k];
    }
}

__global__ __launch_bounds__(256) void fill_kernel(const int* __restrict__ dst,
                                                   int* __restrict__ cursor,
                                                   int* __restrict__ eids) {
    for (int i = blockIdx.x * blockDim.x + threadIdx.x; i < GE; i += gridDim.x * blockDim.x) {
        int pos = atomicAdd(&cursor[dst[i]], 1);
        eids[pos] = i;
    }
}

// ---------------- reorder into CSR order (tier A only) ----------------

__global__ __launch_bounds__(256) void reorder_src_kernel(const int* __restrict__ eids,
                                                          const int* __restrict__ srcArr,
                                                          int* __restrict__ out) {
    for (int p = blockIdx.x * blockDim.x + threadIdx.x; p < GE; p += gridDim.x * blockDim.x)
        out[p] = srcArr[eids[p]];
}

__global__ __launch_bounds__(256) void reorder_attr_kernel(const int* __restrict__ eids,
                                                           const float4* __restrict__ attr,
                                                           float4* __restrict__ out) {
    for (int t = blockIdx.x * blockDim.x + threadIdx.x; t < GE * 4; t += gridDim.x * blockDim.x) {
        int p = t >> 2, q = t & 3;
        out[t] = attr[(size_t)eids[p] * 4 + q];
    }
}

// ---------------- column stats (standalone, for x) ----------------

__global__ __launch_bounds__(256) void col_stats64(const float* __restrict__ in,
                                                   float* __restrict__ sum,
                                                   float* __restrict__ sq) {
    int c = threadIdx.x & 63;
    int lr = threadIdx.x >> 6;
    float s = 0.f, q = 0.f;
    for (int r = blockIdx.x * 4 + lr; r < GN; r += gridDim.x * 4) {
        float v = in[(size_t)r * 64 + c];
        s += v;
        q += v * v;
    }
    __shared__ float S[256];
    S[threadIdx.x] = s;
    __syncthreads();
    if (threadIdx.x < 64) {
        float a = S[threadIdx.x] + S[threadIdx.x + 64] + S[threadIdx.x + 128] + S[threadIdx.x + 192];
        atomicAdd(&sum[threadIdx.x], a);
    }
    __syncthreads();
    S[threadIdx.x] = q;
    __syncthreads();
    if (threadIdx.x < 64) {
        float a = S[threadIdx.x] + S[threadIdx.x + 64] + S[threadIdx.x + 128] + S[threadIdx.x + 192];
        atomicAdd(&sq[threadIdx.x], a);
    }
}

// ---------------- fused BN(pre) + GINE aggregation ----------------
// One wave per node (lane = feature dim). Batch-load 64 src indices coalesced,
// shuffle-broadcast, unroll the h-gathers x4 for memory-level parallelism.

__device__ __forceinline__ float edot16(const float* __restrict__ row, float4 w0, float4 w1,
                                        float4 w2, float4 w3) {
    const float4* a = (const float4*)row;
    float4 a0 = a[0], a1 = a[1], a2 = a[2], a3 = a[3];
    return a0.x * w0.x + a0.y * w0.y + a0.z * w0.z + a0.w * w0.w +
           a1.x * w1.x + a1.y * w1.y + a1.z * w1.z + a1.w * w1.w +
           a2.x * w2.x + a2.y * w2.y + a2.z * w2.z + a2.w * w2.w +
           a3.x * w3.x + a3.y * w3.y + a3.z * w3.z + a3.w * w3.w;
}

template <bool SORTED>
__global__ __launch_bounds__(256) void aggregate_kernel(
    const float* __restrict__ h,
    const float* __restrict__ sumv, const float* __restrict__ sqv,
    const float* __restrict__ bnw, const float* __restrict__ bnb,
    int leaky,
    const int* __restrict__ off,
    const int* __restrict__ idxArr,   // SORTED: src_sorted ; else: eids
    const int* __restrict__ srcArr,   // used only when !SORTED
    const float* __restrict__ attr,   // SORTED: attr_sorted ; else: raw attr
    const float* __restrict__ Wle, const float* __restrict__ ble,
    const float* __restrict__ epsArr, int layer,
    float* __restrict__ z) {
    int node = blockIdx.x * 4 + (threadIdx.x >> 6);
    int d = threadIdx.x & 63;
    if (node >= GN) return;

    float mean = sumv[d] / FN;
    float var = sqv[d] / FN - mean * mean;
    float cA = rsqrtf(var + BN_EPS) * bnw[d];
    float cB = bnb[d] - mean * cA;

    const float4* wp = (const float4*)(Wle + d * 16);
    float4 w0 = wp[0], w1 = wp[1], w2 = wp[2], w3 = wp[3];
    float be = ble[d];
    float epsv = 1.0f + epsArr[layer];

    int p0 = off[node], p1 = off[node + 1];
    float acc = 0.0f;

    for (int base = p0; base < p1; base += 64) {
        int cnt = p1 - base;
        if (cnt > 64) cnt = 64;
        int iv = (base + d < p1) ? idxArr[base + d] : 0;  // coalesced batch load
        int j = 0;
        for (; j + 4 <= cnt; j += 4) {
            int t0 = __shfl(iv, j), t1 = __shfl(iv, j + 1);
            int t2 = __shfl(iv, j + 2), t3 = __shfl(iv, j + 3);
            int s0, s1, s2, s3;
            size_t r0, r1, r2, r3;
            if (SORTED) {
                s0 = t0; s1 = t1; s2 = t2; s3 = t3;
                r0 = (size_t)(base + j) * 16; r1 = r0 + 16; r2 = r0 + 32; r3 = r0 + 48;
            } else {
                s0 = srcArr[t0]; s1 = srcArr[t1]; s2 = srcArr[t2]; s3 = srcArr[t3];
                r0 = (size_t)t0 * 16; r1 = (size_t)t1 * 16;
                r2 = (size_t)t2 * 16; r3 = (size_t)t3 * 16;
            }
            float g0 = h[(size_t)s0 * 64 + d];
            float g1 = h[(size_t)s1 * 64 + d];
            float g2 = h[(size_t)s2 * 64 + d];
            float g3 = h[(size_t)s3 * 64 + d];
            float e0 = edot16(attr + r0, w0, w1, w2, w3) + be;
            float e1 = edot16(attr + r1, w0, w1, w2, w3) + be;
            float e2 = edot16(attr + r2, w0, w1, w2, w3) + be;
            float e3 = edot16(attr + r3, w0, w1, w2, w3) + be;
            g0 = g0 * cA + cB; g1 = g1 * cA + cB;
            g2 = g2 * cA + cB; g3 = g3 * cA + cB;
            if (leaky) {
                g0 = g0 > 0.f ? g0 : 0.01f * g0;
                g1 = g1 > 0.f ? g1 : 0.01f * g1;
                g2 = g2 > 0.f ? g2 : 0.01f * g2;
                g3 = g3 > 0.f ? g3 : 0.01f * g3;
            }
            acc += fmaxf(g0 + e0, 0.f) + fmaxf(g1 + e1, 0.f) +
                   fmaxf(g2 + e2, 0.f) + fmaxf(g3 + e3, 0.f);
        }
        for (; j < cnt; ++j) {
            int t0 = __shfl(iv, j);
            int s0 = SORTED ? t0 : srcArr[t0];
            size_t r0 = SORTED ? (size_t)(base + j) * 16 : (size_t)t0 * 16;
            float g0 = h[(size_t)s0 * 64 + d];
            float e0 = edot16(attr + r0, w0, w1, w2, w3) + be;
            g0 = g0 * cA + cB;
            if (leaky) g0 = g0 > 0.f ? g0 : 0.01f * g0;
            acc += fmaxf(g0 + e0, 0.f);
        }
    }
    float hv = h[(size_t)node * 64 + d] * cA + cB;
    if (leaky) hv = hv > 0.f ? hv : 0.01f * hv;
    z[(size_t)node * 64 + d] = epsv * hv + acc;
}

// ---------------- tiled GEMM: dst = f(src) @ W^T + bias [+resid], fused stats ----------------

template <bool BN_IN>
__global__ __launch_bounds__(256) void gemm64(
    const float* __restrict__ src, int src_ld,
    const float* __restrict__ W, const float* __restrict__ bias,
    float* __restrict__ dst, int dst_ld,
    const float* __restrict__ resid,
    const float* __restrict__ statsInSum, const float* __restrict__ statsInSq,
    const float* __restrict__ bnw, const float* __restrict__ bnb,
    float* __restrict__ statsOutSum, float* __restrict__ statsOutSq) {
    __shared__ float Wl[64][68];
    __shared__ float Zl[64][68];
    __shared__ float cA[64], cB[64];
    int tid = threadIdx.x;
    int r0 = blockIdx.x * 64;
    int c0 = blockIdx.y * 64;

    if (BN_IN) {
        if (tid < 64) {
            float m = statsInSum[tid] / FN;
            float var = statsInSq[tid] / FN - m * m;
            float a = rsqrtf(var + BN_EPS) * bnw[tid];
            cA[tid] = a;
            cB[tid] = bnb[tid] - m * a;
        }
        __syncthreads();
    }

    const float* Wt = W + (size_t)c0 * 64;
#pragma unroll
    for (int j = 0; j < 4; ++j) {
        int idx = tid + j * 256;
        int row = idx >> 4, c4 = idx & 15;
        float4 v = *(const float4*)(Wt + (size_t)row * 64 + c4 * 4);
        *(float4*)&Wl[row][c4 * 4] = v;
    }
#pragma unroll
    for (int j = 0; j < 4; ++j) {
        int idx = tid + j * 256;
        int row = idx >> 4, c4 = idx & 15;
        int gr = r0 + row;
        float4 v;
        if (gr < GN) v = *(const float4*)(src + (size_t)gr * src_ld + c4 * 4);
        else { v.x = v.y = v.z = v.w = 0.f; }
        if (BN_IN) {
            int c = c4 * 4;
            v.x = v.x * cA[c + 0] + cB[c + 0];
            v.y = v.y * cA[c + 1] + cB[c + 1];
            v.z = v.z * cA[c + 2] + cB[c + 2];
            v.w = v.w * cA[c + 3] + cB[c + 3];
            v.x = v.x > 0.f ? v.x : 0.01f * v.x;
            v.y = v.y > 0.f ? v.y : 0.01f * v.y;
            v.z = v.z > 0.f ? v.z : 0.01f * v.z;
            v.w = v.w > 0.f ? v.w : 0.01f * v.w;
        }
        *(float4*)&Zl[row][c4 * 4] = v;
    }
    __syncthreads();

    int rg = tid >> 4, cg = tid & 15;
    float acc[4][4];
#pragma unroll
    for (int i = 0; i < 4; ++i)
#pragma unroll
        for (int j = 0; j < 4; ++j) acc[i][j] = 0.f;

#pragma unroll
    for (int k4 = 0; k4 < 16; ++k4) {
        float4 zr[4], wc[4];
#pragma unroll
        for (int rr = 0; rr < 4; ++rr) zr[rr] = *(const float4*)&Zl[rg * 4 + rr][k4 * 4];
#pragma unroll
        for (int cc = 0; cc < 4; ++cc) wc[cc] = *(const float4*)&Wl[cg * 4 + cc][k4 * 4];
#pragma unroll
        for (int rr = 0; rr < 4; ++rr)
#pragma unroll
            for (int cc = 0; cc < 4; ++cc)
                acc[rr][cc] += zr[rr].x * wc[cc].x + zr[rr].y * wc[cc].y +
                               zr[rr].z * wc[cc].z + zr[rr].w * wc[cc].w;
    }

    float colS[4] = {0.f, 0.f, 0.f, 0.f};
    float colQ[4] = {0.f, 0.f, 0.f, 0.f};
#pragma unroll
    for (int rr = 0; rr < 4; ++rr) {
        int gr = r0 + rg * 4 + rr;
        if (gr < GN) {
            float o[4];
#pragma unroll
            for (int cc = 0; cc < 4; ++cc) o[cc] = acc[rr][cc] + bias[c0 + cg * 4 + cc];
            if (resid) {
                float4 rv = *(const float4*)(resid + (size_t)gr * dst_ld + c0 + cg * 4);
                o[0] += rv.x; o[1] += rv.y; o[2] += rv.z; o[3] += rv.w;
            }
            float4 ov; ov.x = o[0]; ov.y = o[1]; ov.z = o[2]; ov.w = o[3];
            *(float4*)(dst + (size_t)gr * dst_ld + c0 + cg * 4) = ov;
#pragma unroll
            for (int cc = 0; cc < 4; ++cc) { colS[cc] += o[cc]; colQ[cc] += o[cc] * o[cc]; }
        }
    }

    if (statsOutSum) {
        float* S = &Zl[0][0];
        __syncthreads();
#pragma unroll
        for (int cc = 0; cc < 4; ++cc) S[(cg * 4 + cc) * 16 + rg] = colS[cc];
        __syncthreads();
        if (tid < 64) {
            float s = 0.f;
#pragma unroll
            for (int j = 0; j < 16; ++j) s += S[tid * 16 + j];
            atomicAdd(&statsOutSum[c0 + tid], s);
        }
        __syncthreads();
#pragma unroll
        for (int cc = 0; cc < 4; ++cc) S[(cg * 4 + cc) * 16 + rg] = colQ[cc];
        __syncthreads();
        if (tid < 64) {
            float s = 0.f;
#pragma unroll
            for (int j = 0; j < 16; ++j) s += S[tid * 16 + j];
            atomicAdd(&statsOutSq[c0 + tid], s);
        }
    }
}

// ---------------- classifier tail ----------------

__global__ __launch_bounds__(256) void cls2_kernel(
    const float* __restrict__ y1,
    const float* __restrict__ sum, const float* __restrict__ sq,
    const float* __restrict__ bnw, const float* __restrict__ bnb,
    const float* __restrict__ w2, const float* __restrict__ b2,
    float* __restrict__ out) {
    int node = blockIdx.x * 4 + (threadIdx.x >> 6);
    int d = threadIdx.x & 63;
    if (node >= GN) return;
    float partial = 0.f;
#pragma unroll
    for (int hh = 0; hh < 2; ++hh) {
        int c = d + hh * 64;
        float m = sum[c] / FN;
        float var = sq[c] / FN - m * m;
        float a = rsqrtf(var + BN_EPS) * bnw[c];
        float v = y1[(size_t)node * 128 + c];
        v = v * a + (bnb[c] - m * a);
        v = v > 0.f ? v : 0.01f * v;
        partial += v * w2[c];
    }
    for (int o = 32; o >= 1; o >>= 1) partial += __shfl_down(partial, o, 64);
    if (d == 0) out[node] = partial + b2[0];
}

// ---------------- launcher ----------------

extern "C" void kernel_launch(void* const* d_in, const int* in_sizes, int n_in,
                              void* d_out, int out_size, void* d_ws, size_t ws_size,
                              hipStream_t stream) {
    (void)in_sizes; (void)n_in; (void)out_size;
    const float* x    = (const float*)d_in[0];
    const int*   ei   = (const int*)d_in[1];
    const float* attr = (const float*)d_in[2];
    const float* bnpw = (const float*)d_in[3];
    const float* bnpb = (const float*)d_in[4];
    const float* elw  = (const float*)d_in[5];
    const float* elb  = (const float*)d_in[6];
    const float* l1w  = (const float*)d_in[7];
    const float* l1b  = (const float*)d_in[8];
    const float* bnmw = (const float*)d_in[9];
    const float* bnmb = (const float*)d_in[10];
    const float* l2w  = (const float*)d_in[11];
    const float* l2b  = (const float*)d_in[12];
    const float* epsA = (const float*)d_in[13];
    const float* c1w  = (const float*)d_in[14];
    const float* c1b  = (const float*)d_in[15];
    const float* cbw  = (const float*)d_in[16];
    const float* cbb  = (const float*)d_in[17];
    const float* c2w  = (const float*)d_in[18];
    const float* c2b  = (const float*)d_in[19];
    const int* srcArr = ei;
    const int* dstArr = ei + GE;

    // tier-A workspace requirement
    size_t needA = 0;
    {
        auto p = [&](size_t b) { needA = (needA + b + 1023) & ~(size_t)1023; };
        p((size_t)(GN + 1) * 4); p((size_t)GN * 4); p((size_t)GE * 4);
        p((size_t)GE * 4); p((size_t)GE * 64);                  // src_sorted, attr_sorted
        p(1024); p(1024); p(512); p(512); p(1024);              // bsum,bbase,stPre,stMid,stCls
        p((size_t)GN * 256); p((size_t)GN * 256);               // h, z
    }
    bool big = ws_size >= needA;

    char* base = (char*)d_ws;
    size_t ofs = 0;
    auto alloc = [&](size_t bytes) {
        void* p = base + ofs;
        ofs = (ofs + bytes + 1023) & ~(size_t)1023;
        return p;
    };
    int* off         = (int*)alloc((size_t)(GN + 1) * 4);
    int* cursor      = (int*)alloc((size_t)GN * 4);
    int* eids        = (int*)alloc((size_t)GE * 4);
    int* src_sorted  = nullptr;
    float* attr_sorted = nullptr;
    if (big) {
        src_sorted  = (int*)alloc((size_t)GE * 4);
        attr_sorted = (float*)alloc((size_t)GE * 64);
    }
    int* bsum   = (int*)alloc(1024);
    int* bbase  = (int*)alloc(1024);
    float* stPre = (float*)alloc(512);
    float* stMid = (float*)alloc(512);
    float* stCls = (float*)alloc(1024);
    float* h = (float*)alloc((size_t)GN * 256);
    float* z = (float*)alloc((size_t)GN * 256);
    float* t = nullptr;
    if (!big) t = (float*)alloc((size_t)GN * 256);  // extends z for y1 [N,128]
    (void)t;
    float* y1 = big ? attr_sorted : z;

    constexpr int NB = (GN + 1023) / 1024;  // 98

    // ---- CSR by dst ----
    hipMemsetAsync(cursor, 0, (size_t)GN * 4, stream);
    hist_kernel<<<2048, 256, 0, stream>>>(dstArr, cursor);
    bsum_kernel<<<NB, 256, 0, stream>>>(cursor, bsum);
    bscan_kernel<<<1, 64, 0, stream>>>(bsum, bbase, off + GN, NB);
    bscatter_kernel<<<NB, 256, 0, stream>>>(cursor, bbase, off);
    hipMemcpyAsync(cursor, off, (size_t)GN * 4, hipMemcpyDeviceToDevice, stream);
    fill_kernel<<<2048, 256, 0, stream>>>(dstArr, cursor, eids);
    if (big) {
        reorder_src_kernel<<<2048, 256, 0, stream>>>(eids, srcArr, src_sorted);
        reorder_attr_kernel<<<4096, 256, 0, stream>>>(eids, (const float4*)attr,
                                                      (float4*)attr_sorted);
    }

    // ---- layer-0 pre-BN stats on x ----
    hipMemsetAsync(stPre, 0, 512, stream);
    col_stats64<<<512, 256, 0, stream>>>(x, stPre, stPre + 64);

    const float* hsrc = x;
    dim3 g1(1563, 1);
    for (int i = 0; i < 4; ++i) {
        if (big)
            aggregate_kernel<true><<<25000, 256, 0, stream>>>(
                hsrc, stPre, stPre + 64, bnpw + i * 64, bnpb + i * 64, (i > 0) ? 1 : 0,
                off, src_sorted, nullptr, attr_sorted, elw + i * 1024, elb + i * 64,
                epsA, i, z);
        else
            aggregate_kernel<false><<<25000, 256, 0, stream>>>(
                hsrc, stPre, stPre + 64, bnpw + i * 64, bnpb + i * 64, (i > 0) ? 1 : 0,
                off, eids, srcArr, attr, elw + i * 1024, elb + i * 64, epsA, i, z);
        hipMemsetAsync(stMid, 0, 512, stream);
        gemm64<false><<<g1, 256, 0, stream>>>(
            z, 64, l1w + i * 4096, l1b + i * 64, z, 64, nullptr,
            nullptr, nullptr, nullptr, nullptr, stMid, stMid + 64);
        hipMemsetAsync(stPre, 0, 512, stream);
        gemm64<true><<<g1, 256, 0, stream>>>(
            z, 64, l2w + i * 4096, l2b + i * 64, h, 64, (i > 0) ? h : nullptr,
            stMid, stMid + 64, bnmw + i * 64, bnmb + i * 64, stPre, stPre + 64);
        hsrc = h;
    }

    // ---- classifier ----
    hipMemsetAsync(stCls, 0, 1024, stream);
    dim3 gc(1563, 2);
    gemm64<false><<<gc, 256, 0, stream>>>(
        h, 64, c1w, c1b, y1, 128, nullptr,
        nullptr, nullptr, nullptr, nullptr, stCls, stCls + 128);
    cls2_kernel<<<25000, 256, 0, stream>>>(y1, stCls, stCls + 128, cbw, cbb, c2w, c2b,
                                           (float*)d_out);
}

// Round 3
// 1602.280 us; speedup vs baseline: 1.5645x; 1.3132x over previous
//
#include <hip/hip_runtime.h>

// Problem constants (fixed by reference)
constexpr int GN = 100000;   // nodes
constexpr int GE = 1600000;  // edges
constexpr float FN = 100000.0f;
constexpr float BN_EPS = 1e-5f;

// ---------------- CSR build ----------------

__global__ __launch_bounds__(256) void hist_kernel(const int* __restrict__ dst,
                                                   int* __restrict__ deg) {
    for (int i = blockIdx.x * blockDim.x + threadIdx.x; i < GE; i += gridDim.x * blockDim.x)
        atomicAdd(&deg[dst[i]], 1);
}

// hierarchical exclusive scan of deg[0..GN) -> off[0..GN], off[GN]=total
__global__ __launch_bounds__(256) void bsum_kernel(const int* __restrict__ deg,
                                                   int* __restrict__ bsum) {
    int b = blockIdx.x;
    int i0 = b * 1024 + threadIdx.x * 4;
    int s = 0;
#pragma unroll
    for (int k = 0; k < 4; ++k) {
        int i = i0 + k;
        if (i < GN) s += deg[i];
    }
    for (int o = 32; o >= 1; o >>= 1) s += __shfl_down(s, o, 64);
    __shared__ int ws[4];
    if ((threadIdx.x & 63) == 0) ws[threadIdx.x >> 6] = s;
    __syncthreads();
    if (threadIdx.x == 0) bsum[b] = ws[0] + ws[1] + ws[2] + ws[3];
}

__global__ void bscan_kernel(const int* __restrict__ bsum, int* __restrict__ bbase,
                             int* __restrict__ offEnd, int nb) {
    int t = threadIdx.x;  // 64 threads, 1 wave
    int carry = 0;
    for (int base = 0; base < nb; base += 64) {
        int v = (base + t < nb) ? bsum[base + t] : 0;
        int incl = v;
        for (int o = 1; o < 64; o <<= 1) {
            int u = __shfl_up(incl, o, 64);
            if (t >= o) incl += u;
        }
        if (base + t < nb) bbase[base + t] = carry + incl - v;
        carry += __shfl(incl, 63, 64);
    }
    if (t == 0) offEnd[0] = carry;
}

// writes exclusive prefix to BOTH off[] and (in place) cursor[] (== deg array)
__global__ __launch_bounds__(256) void bscatter_kernel(int* __restrict__ deg,
                                                       const int* __restrict__ bbase,
                                                       int* __restrict__ off) {
    int b = blockIdx.x;
    int t = threadIdx.x;
    int i0 = b * 1024 + t * 4;
    int v[4];
    int s = 0;
#pragma unroll
    for (int k = 0; k < 4; ++k) {
        int i = i0 + k;
        v[k] = (i < GN) ? deg[i] : 0;
        s += v[k];
    }
    int incl = s;
    int lane = t & 63;
    for (int o = 1; o < 64; o <<= 1) {
        int u = __shfl_up(incl, o, 64);
        if (lane >= o) incl += u;
    }
    __shared__ int wsum[4];
    if (lane == 63) wsum[t >> 6] = incl;
    __syncthreads();
    int w = t >> 6;
    int wb = 0;
#pragma unroll
    for (int k = 0; k < 4; ++k)
        if (k < w) wb += wsum[k];
    int ex = bbase[b] + wb + incl - s;
#pragma unroll
    for (int k = 0; k < 4; ++k) {
        int i = i0 + k;
        if (i < GN) { off[i] = ex; deg[i] = ex; }
        ex += v[k];
    }
}

// counting-sort fill: writes src_sorted and attr_sorted directly (no eids pass)
__global__ __launch_bounds__(256) void fill_sorted_kernel(
    const int* __restrict__ src, const int* __restrict__ dst,
    const float4* __restrict__ attr,
    int* __restrict__ cursor,
    int* __restrict__ srcS, float4* __restrict__ attrS) {
    for (int i = blockIdx.x * blockDim.x + threadIdx.x; i < GE; i += gridDim.x * blockDim.x) {
        int pos = atomicAdd(&cursor[dst[i]], 1);
        srcS[pos] = src[i];
        size_t r = (size_t)i * 4, w = (size_t)pos * 4;
        float4 a0 = attr[r], a1 = attr[r + 1], a2 = attr[r + 2], a3 = attr[r + 3];
        attrS[w] = a0; attrS[w + 1] = a1; attrS[w + 2] = a2; attrS[w + 3] = a3;
    }
}

// ---------------- column stats (standalone, for x) ----------------

__global__ __launch_bounds__(256) void col_stats64(const float* __restrict__ in,
                                                   float* __restrict__ sum,
                                                   float* __restrict__ sq) {
    int c = threadIdx.x & 63;
    int lr = threadIdx.x >> 6;
    float s = 0.f, q = 0.f;
    for (int r = blockIdx.x * 4 + lr; r < GN; r += gridDim.x * 4) {
        float v = in[(size_t)r * 64 + c];
        s += v;
        q += v * v;
    }
    __shared__ float S[256];
    S[threadIdx.x] = s;
    __syncthreads();
    if (threadIdx.x < 64) {
        float a = S[threadIdx.x] + S[threadIdx.x + 64] + S[threadIdx.x + 128] + S[threadIdx.x + 192];
        atomicAdd(&sum[threadIdx.x], a);
    }
    __syncthreads();
    S[threadIdx.x] = q;
    __syncthreads();
    if (threadIdx.x < 64) {
        float a = S[threadIdx.x] + S[threadIdx.x + 64] + S[threadIdx.x + 128] + S[threadIdx.x + 192];
        atomicAdd(&sq[threadIdx.x], a);
    }
}

// ---------------- fused BN(pre) + GINE aggregation, scalar-path ----------------
// One wave per node; node forced wave-uniform via readfirstlane so that index
// and attr loads become s_load (scalar cache), leaving only the h row-gather
// on the vector path. Masked unroll-8 keeps 8 gathers in flight always.

__device__ __forceinline__ float edot16(const float* __restrict__ row, float4 w0, float4 w1,
                                        float4 w2, float4 w3) {
    const float4* a = (const float4*)row;
    float4 a0 = a[0], a1 = a[1], a2 = a[2], a3 = a[3];
    return a0.x * w0.x + a0.y * w0.y + a0.z * w0.z + a0.w * w0.w +
           a1.x * w1.x + a1.y * w1.y + a1.z * w1.z + a1.w * w1.w +
           a2.x * w2.x + a2.y * w2.y + a2.z * w2.z + a2.w * w2.w +
           a3.x * w3.x + a3.y * w3.y + a3.z * w3.z + a3.w * w3.w;
}

__global__ __launch_bounds__(256) void aggregate_kernel(
    const float* __restrict__ h,
    const float* __restrict__ sumv, const float* __restrict__ sqv,
    const float* __restrict__ bnw, const float* __restrict__ bnb,
    int leaky,
    const int* __restrict__ off,
    const int* __restrict__ srcS,
    const float* __restrict__ attrS,
    const float* __restrict__ Wle, const float* __restrict__ ble,
    const float* __restrict__ epsArr, int layer,
    float* __restrict__ z) {
    const int d = threadIdx.x & 63;
    const int node = __builtin_amdgcn_readfirstlane(blockIdx.x * 4 + (threadIdx.x >> 6));

    float mean = sumv[d] / FN;
    float var = sqv[d] / FN - mean * mean;
    float cA = rsqrtf(var + BN_EPS) * bnw[d];
    float cB = bnb[d] - mean * cA;
    const float4* wp = (const float4*)(Wle + d * 16);
    float4 w0 = wp[0], w1 = wp[1], w2 = wp[2], w3 = wp[3];
    float be = ble[d];
    float epsv = 1.0f + epsArr[layer];

    int p0 = off[node], p1 = off[node + 1];  // uniform -> s_load
    float hv = h[(size_t)node * 64 + d];     // issue early

    float acc = 0.0f;
    for (int p = p0; p < p1; p += 8) {
        int idx[8];
        float g[8], e[8];
#pragma unroll
        for (int j = 0; j < 8; ++j) {
            int q = p + j;
            if (q > p1 - 1) q = p1 - 1;      // uniform clamp (s_min)
            idx[j] = srcS[q];                // uniform -> s_load
        }
#pragma unroll
        for (int j = 0; j < 8; ++j)
            g[j] = h[(size_t)idx[j] * 64 + d];  // 8 vector gathers in flight
#pragma unroll
        for (int j = 0; j < 8; ++j) {
            int q = p + j;
            if (q > p1 - 1) q = p1 - 1;
            e[j] = edot16(attrS + (size_t)q * 16, w0, w1, w2, w3) + be;  // uniform rows
        }
#pragma unroll
        for (int j = 0; j < 8; ++j) {
            float gg = g[j] * cA + cB;
            if (leaky) gg = gg > 0.f ? gg : 0.01f * gg;
            float m = fmaxf(gg + e[j], 0.f);
            acc += (p + j < p1) ? m : 0.f;
        }
    }
    hv = hv * cA + cB;
    if (leaky) hv = hv > 0.f ? hv : 0.01f * hv;
    z[(size_t)node * 64 + d] = epsv * hv + acc;
}

// ---------------- tiled GEMM: dst = f(src) @ W^T + bias [+resid], fused stats ----------------

template <bool BN_IN>
__global__ __launch_bounds__(256) void gemm64(
    const float* __restrict__ src, int src_ld,
    const float* __restrict__ W, const float* __restrict__ bias,
    float* __restrict__ dst, int dst_ld,
    const float* __restrict__ resid,
    const float* __restrict__ statsInSum, const float* __restrict__ statsInSq,
    const float* __restrict__ bnw, const float* __restrict__ bnb,
    float* __restrict__ statsOutSum, float* __restrict__ statsOutSq) {
    __shared__ float Wl[64][68];
    __shared__ float Zl[64][68];
    __shared__ float cA[64], cB[64];
    int tid = threadIdx.x;
    int r0 = blockIdx.x * 64;
    int c0 = blockIdx.y * 64;

    if (BN_IN) {
        if (tid < 64) {
            float m = statsInSum[tid] / FN;
            float var = statsInSq[tid] / FN - m * m;
            float a = rsqrtf(var + BN_EPS) * bnw[tid];
            cA[tid] = a;
            cB[tid] = bnb[tid] - m * a;
        }
        __syncthreads();
    }

    const float* Wt = W + (size_t)c0 * 64;
#pragma unroll
    for (int j = 0; j < 4; ++j) {
        int idx = tid + j * 256;
        int row = idx >> 4, c4 = idx & 15;
        float4 v = *(const float4*)(Wt + (size_t)row * 64 + c4 * 4);
        *(float4*)&Wl[row][c4 * 4] = v;
    }
#pragma unroll
    for (int j = 0; j < 4; ++j) {
        int idx = tid + j * 256;
        int row = idx >> 4, c4 = idx & 15;
        int gr = r0 + row;
        float4 v;
        if (gr < GN) v = *(const float4*)(src + (size_t)gr * src_ld + c4 * 4);
        else { v.x = v.y = v.z = v.w = 0.f; }
        if (BN_IN) {
            int c = c4 * 4;
            v.x = v.x * cA[c + 0] + cB[c + 0];
            v.y = v.y * cA[c + 1] + cB[c + 1];
            v.z = v.z * cA[c + 2] + cB[c + 2];
            v.w = v.w * cA[c + 3] + cB[c + 3];
            v.x = v.x > 0.f ? v.x : 0.01f * v.x;
            v.y = v.y > 0.f ? v.y : 0.01f * v.y;
            v.z = v.z > 0.f ? v.z : 0.01f * v.z;
            v.w = v.w > 0.f ? v.w : 0.01f * v.w;
        }
        *(float4*)&Zl[row][c4 * 4] = v;
    }
    __syncthreads();

    int rg = tid >> 4, cg = tid & 15;
    float acc[4][4];
#pragma unroll
    for (int i = 0; i < 4; ++i)
#pragma unroll
        for (int j = 0; j < 4; ++j) acc[i][j] = 0.f;

#pragma unroll
    for (int k4 = 0; k4 < 16; ++k4) {
        float4 zr[4], wc[4];
#pragma unroll
        for (int rr = 0; rr < 4; ++rr) zr[rr] = *(const float4*)&Zl[rg * 4 + rr][k4 * 4];
#pragma unroll
        for (int cc = 0; cc < 4; ++cc) wc[cc] = *(const float4*)&Wl[cg * 4 + cc][k4 * 4];
#pragma unroll
        for (int rr = 0; rr < 4; ++rr)
#pragma unroll
            for (int cc = 0; cc < 4; ++cc)
                acc[rr][cc] += zr[rr].x * wc[cc].x + zr[rr].y * wc[cc].y +
                               zr[rr].z * wc[cc].z + zr[rr].w * wc[cc].w;
    }

    float colS[4] = {0.f, 0.f, 0.f, 0.f};
    float colQ[4] = {0.f, 0.f, 0.f, 0.f};
#pragma unroll
    for (int rr = 0; rr < 4; ++rr) {
        int gr = r0 + rg * 4 + rr;
        if (gr < GN) {
            float o[4];
#pragma unroll
            for (int cc = 0; cc < 4; ++cc) o[cc] = acc[rr][cc] + bias[c0 + cg * 4 + cc];
            if (resid) {
                float4 rv = *(const float4*)(resid + (size_t)gr * dst_ld + c0 + cg * 4);
                o[0] += rv.x; o[1] += rv.y; o[2] += rv.z; o[3] += rv.w;
            }
            float4 ov; ov.x = o[0]; ov.y = o[1]; ov.z = o[2]; ov.w = o[3];
            *(float4*)(dst + (size_t)gr * dst_ld + c0 + cg * 4) = ov;
#pragma unroll
            for (int cc = 0; cc < 4; ++cc) { colS[cc] += o[cc]; colQ[cc] += o[cc] * o[cc]; }
        }
    }

    if (statsOutSum) {
        float* S = &Zl[0][0];
        __syncthreads();
#pragma unroll
        for (int cc = 0; cc < 4; ++cc) S[(cg * 4 + cc) * 16 + rg] = colS[cc];
        __syncthreads();
        if (tid < 64) {
            float s = 0.f;
#pragma unroll
            for (int j = 0; j < 16; ++j) s += S[tid * 16 + j];
            atomicAdd(&statsOutSum[c0 + tid], s);
        }
        __syncthreads();
#pragma unroll
        for (int cc = 0; cc < 4; ++cc) S[(cg * 4 + cc) * 16 + rg] = colQ[cc];
        __syncthreads();
        if (tid < 64) {
            float s = 0.f;
#pragma unroll
            for (int j = 0; j < 16; ++j) s += S[tid * 16 + j];
            atomicAdd(&statsOutSq[c0 + tid], s);
        }
    }
}

// ---------------- classifier tail ----------------

__global__ __launch_bounds__(256) void cls2_kernel(
    const float* __restrict__ y1,
    const float* __restrict__ sum, const float* __restrict__ sq,
    const float* __restrict__ bnw, const float* __restrict__ bnb,
    const float* __restrict__ w2, const float* __restrict__ b2,
    float* __restrict__ out) {
    int node = blockIdx.x * 4 + (threadIdx.x >> 6);
    int d = threadIdx.x & 63;
    if (node >= GN) return;
    float partial = 0.f;
#pragma unroll
    for (int hh = 0; hh < 2; ++hh) {
        int c = d + hh * 64;
        float m = sum[c] / FN;
        float var = sq[c] / FN - m * m;
        float a = rsqrtf(var + BN_EPS) * bnw[c];
        float v = y1[(size_t)node * 128 + c];
        v = v * a + (bnb[c] - m * a);
        v = v > 0.f ? v : 0.01f * v;
        partial += v * w2[c];
    }
    for (int o = 32; o >= 1; o >>= 1) partial += __shfl_down(partial, o, 64);
    if (d == 0) out[node] = partial + b2[0];
}

// ---------------- launcher ----------------

extern "C" void kernel_launch(void* const* d_in, const int* in_sizes, int n_in,
                              void* d_out, int out_size, void* d_ws, size_t ws_size,
                              hipStream_t stream) {
    (void)in_sizes; (void)n_in; (void)out_size; (void)ws_size;
    const float* x    = (const float*)d_in[0];
    const int*   ei   = (const int*)d_in[1];
    const float* attr = (const float*)d_in[2];
    const float* bnpw = (const float*)d_in[3];
    const float* bnpb = (const float*)d_in[4];
    const float* elw  = (const float*)d_in[5];
    const float* elb  = (const float*)d_in[6];
    const float* l1w  = (const float*)d_in[7];
    const float* l1b  = (const float*)d_in[8];
    const float* bnmw = (const float*)d_in[9];
    const float* bnmb = (const float*)d_in[10];
    const float* l2w  = (const float*)d_in[11];
    const float* l2b  = (const float*)d_in[12];
    const float* epsA = (const float*)d_in[13];
    const float* c1w  = (const float*)d_in[14];
    const float* c1b  = (const float*)d_in[15];
    const float* cbw  = (const float*)d_in[16];
    const float* cbb  = (const float*)d_in[17];
    const float* c2w  = (const float*)d_in[18];
    const float* c2b  = (const float*)d_in[19];
    const int* srcArr = ei;
    const int* dstArr = ei + GE;

    char* base = (char*)d_ws;
    size_t ofs = 0;
    auto alloc = [&](size_t bytes) {
        void* p = base + ofs;
        ofs = (ofs + bytes + 1023) & ~(size_t)1023;
        return p;
    };
    int* off          = (int*)alloc((size_t)(GN + 1) * 4);
    int* cursor       = (int*)alloc((size_t)GN * 4);      // doubles as deg
    int* src_sorted   = (int*)alloc((size_t)GE * 4);
    float* attr_sorted = (float*)alloc((size_t)GE * 64);
    int* bsum   = (int*)alloc(1024);
    int* bbase  = (int*)alloc(1024);
    float* stPre = (float*)alloc(512);
    float* stMid = (float*)alloc(512);
    float* stCls = (float*)alloc(1024);
    float* h = (float*)alloc((size_t)GN * 256);
    float* z = (float*)alloc((size_t)GN * 256);
    float* y1 = attr_sorted;  // reuse (needs N*128*4 = 51.2MB <= 102.4MB)

    constexpr int NB = (GN + 1023) / 1024;  // 98

    // ---- CSR by dst, with direct sorted-materialization ----
    hipMemsetAsync(cursor, 0, (size_t)GN * 4, stream);
    hist_kernel<<<2048, 256, 0, stream>>>(dstArr, cursor);
    bsum_kernel<<<NB, 256, 0, stream>>>(cursor, bsum);
    bscan_kernel<<<1, 64, 0, stream>>>(bsum, bbase, off + GN, NB);
    bscatter_kernel<<<NB, 256, 0, stream>>>(cursor, bbase, off);
    fill_sorted_kernel<<<2048, 256, 0, stream>>>(srcArr, dstArr, (const float4*)attr,
                                                 cursor, src_sorted, (float4*)attr_sorted);

    // ---- layer-0 pre-BN stats on x ----
    hipMemsetAsync(stPre, 0, 512, stream);
    col_stats64<<<512, 256, 0, stream>>>(x, stPre, stPre + 64);

    const float* hsrc = x;
    dim3 g1(1563, 1);
    for (int i = 0; i < 4; ++i) {
        aggregate_kernel<<<25000, 256, 0, stream>>>(
            hsrc, stPre, stPre + 64, bnpw + i * 64, bnpb + i * 64, (i > 0) ? 1 : 0,
            off, src_sorted, attr_sorted, elw + i * 1024, elb + i * 64, epsA, i, z);
        hipMemsetAsync(stMid, 0, 512, stream);
        gemm64<false><<<g1, 256, 0, stream>>>(
            z, 64, l1w + i * 4096, l1b + i * 64, z, 64, nullptr,
            nullptr, nullptr, nullptr, nullptr, stMid, stMid + 64);
        hipMemsetAsync(stPre, 0, 512, stream);
        gemm64<true><<<g1, 256, 0, stream>>>(
            z, 64, l2w + i * 4096, l2b + i * 64, h, 64, (i > 0) ? h : nullptr,
            stMid, stMid + 64, bnmw + i * 64, bnmb + i * 64, stPre, stPre + 64);
        hsrc = h;
    }

    // ---- classifier ----
    hipMemsetAsync(stCls, 0, 1024, stream);
    dim3 gc(1563, 2);
    gemm64<false><<<gc, 256, 0, stream>>>(
        h, 64, c1w, c1b, y1, 128, nullptr,
        nullptr, nullptr, nullptr, nullptr, stCls, stCls + 128);
    cls2_kernel<<<25000, 256, 0, stream>>>(y1, stCls, stCls + 128, cbw, cbb, c2w, c2b,
                                           (float*)d_out);
}

// Round 4
// 1439.555 us; speedup vs baseline: 1.7414x; 1.1130x over previous
//
#include <hip/hip_runtime.h>
#include <hip/hip_bf16.h>

// Problem constants (fixed by reference)
constexpr int GN = 100000;   // nodes
constexpr int GE = 1600000;  // edges
constexpr float FN = 100000.0f;
constexpr float BN_EPS = 1e-5f;

typedef __attribute__((ext_vector_type(8))) short bf16x8;
typedef __attribute__((ext_vector_type(4))) float f32x4;

__device__ __forceinline__ unsigned packbf2(float a, float b) {
    __hip_bfloat162 h = __float22bfloat162_rn(float2{a, b});
    union { __hip_bfloat162 h2; unsigned u; } cv;
    cv.h2 = h;
    return cv.u;
}

__device__ __forceinline__ unsigned short bf16rn(float f) {
    unsigned u = __builtin_bit_cast(unsigned, f);
    unsigned r = (u + 0x7FFF + ((u >> 16) & 1)) >> 16;
    return (unsigned short)r;
}

// ---------------- CSR build ----------------

__global__ __launch_bounds__(256) void hist_kernel(const int* __restrict__ dst,
                                                   int* __restrict__ deg) {
    for (int i = blockIdx.x * blockDim.x + threadIdx.x; i < GE; i += gridDim.x * blockDim.x)
        atomicAdd(&deg[dst[i]], 1);
}

__global__ __launch_bounds__(256) void bsum_kernel(const int* __restrict__ deg,
                                                   int* __restrict__ bsum) {
    int b = blockIdx.x;
    int i0 = b * 1024 + threadIdx.x * 4;
    int s = 0;
#pragma unroll
    for (int k = 0; k < 4; ++k) {
        int i = i0 + k;
        if (i < GN) s += deg[i];
    }
    for (int o = 32; o >= 1; o >>= 1) s += __shfl_down(s, o, 64);
    __shared__ int ws[4];
    if ((threadIdx.x & 63) == 0) ws[threadIdx.x >> 6] = s;
    __syncthreads();
    if (threadIdx.x == 0) bsum[b] = ws[0] + ws[1] + ws[2] + ws[3];
}

__global__ void bscan_kernel(const int* __restrict__ bsum, int* __restrict__ bbase,
                             int* __restrict__ offEnd, int nb) {
    int t = threadIdx.x;  // 64 threads, 1 wave
    int carry = 0;
    for (int base = 0; base < nb; base += 64) {
        int v = (base + t < nb) ? bsum[base + t] : 0;
        int incl = v;
        for (int o = 1; o < 64; o <<= 1) {
            int u = __shfl_up(incl, o, 64);
            if (t >= o) incl += u;
        }
        if (base + t < nb) bbase[base + t] = carry + incl - v;
        carry += __shfl(incl, 63, 64);
    }
    if (t == 0) offEnd[0] = carry;
}

// writes exclusive prefix to BOTH off[] and (in place) cursor[] (== deg array)
__global__ __launch_bounds__(256) void bscatter_kernel(int* __restrict__ deg,
                                                       const int* __restrict__ bbase,
                                                       int* __restrict__ off) {
    int b = blockIdx.x;
    int t = threadIdx.x;
    int i0 = b * 1024 + t * 4;
    int v[4];
    int s = 0;
#pragma unroll
    for (int k = 0; k < 4; ++k) {
        int i = i0 + k;
        v[k] = (i < GN) ? deg[i] : 0;
        s += v[k];
    }
    int incl = s;
    int lane = t & 63;
    for (int o = 1; o < 64; o <<= 1) {
        int u = __shfl_up(incl, o, 64);
        if (lane >= o) incl += u;
    }
    __shared__ int wsum[4];
    if (lane == 63) wsum[t >> 6] = incl;
    __syncthreads();
    int w = t >> 6;
    int wb = 0;
#pragma unroll
    for (int k = 0; k < 4; ++k)
        if (k < w) wb += wsum[k];
    int ex = bbase[b] + wb + incl - s;
#pragma unroll
    for (int k = 0; k < 4; ++k) {
        int i = i0 + k;
        if (i < GN) { off[i] = ex; deg[i] = ex; }
        ex += v[k];
    }
}

// counting-sort fill: writes src_sorted and bf16 attr_sorted directly
__global__ __launch_bounds__(256) void fill_sorted_kernel(
    const int* __restrict__ src, const int* __restrict__ dst,
    const float4* __restrict__ attr,
    int* __restrict__ cursor,
    int* __restrict__ srcS, unsigned* __restrict__ attrS) {
    for (int i = blockIdx.x * blockDim.x + threadIdx.x; i < GE; i += gridDim.x * blockDim.x) {
        int pos = atomicAdd(&cursor[dst[i]], 1);
        srcS[pos] = src[i];
        size_t r = (size_t)i * 4;
        float4 a0 = attr[r], a1 = attr[r + 1], a2 = attr[r + 2], a3 = attr[r + 3];
        uint4 ua, ub;
        ua.x = packbf2(a0.x, a0.y); ua.y = packbf2(a0.z, a0.w);
        ua.z = packbf2(a1.x, a1.y); ua.w = packbf2(a1.z, a1.w);
        ub.x = packbf2(a2.x, a2.y); ub.y = packbf2(a2.z, a2.w);
        ub.z = packbf2(a3.x, a3.y); ub.w = packbf2(a3.z, a3.w);
        uint4* out = (uint4*)(attrS + (size_t)pos * 8);
        out[0] = ua;
        out[1] = ub;
    }
}

// ---------------- weight pre-conversion to bf16 ----------------
// layout: [0,16384) l1w (4 layers x 64x64), [16384,32768) l2w, [32768,40960) c1w

__global__ __launch_bounds__(256) void convw_kernel(const float* __restrict__ l1w,
                                                    const float* __restrict__ l2w,
                                                    const float* __restrict__ c1w,
                                                    unsigned short* __restrict__ wb) {
    int i = blockIdx.x * 256 + threadIdx.x;
    if (i >= 40960) return;
    float v;
    if (i < 16384) v = l1w[i];
    else if (i < 32768) v = l2w[i - 16384];
    else v = c1w[i - 32768];
    wb[i] = bf16rn(v);
}

// ---------------- column stats (standalone, for x) ----------------

__global__ __launch_bounds__(256) void col_stats64(const float* __restrict__ in,
                                                   float* __restrict__ sum,
                                                   float* __restrict__ sq) {
    int c = threadIdx.x & 63;
    int lr = threadIdx.x >> 6;
    float s = 0.f, q = 0.f;
    for (int r = blockIdx.x * 4 + lr; r < GN; r += gridDim.x * 4) {
        float v = in[(size_t)r * 64 + c];
        s += v;
        q += v * v;
    }
    __shared__ float S[256];
    S[threadIdx.x] = s;
    __syncthreads();
    if (threadIdx.x < 64) {
        float a = S[threadIdx.x] + S[threadIdx.x + 64] + S[threadIdx.x + 128] + S[threadIdx.x + 192];
        atomicAdd(&sum[threadIdx.x], a);
    }
    __syncthreads();
    S[threadIdx.x] = q;
    __syncthreads();
    if (threadIdx.x < 64) {
        float a = S[threadIdx.x] + S[threadIdx.x + 64] + S[threadIdx.x + 128] + S[threadIdx.x + 192];
        atomicAdd(&sq[threadIdx.x], a);
    }
}

// ---------------- fused BN(pre) + GINE aggregation, scalar-path ----------------

__device__ __forceinline__ float bhalf2(unsigned u, float wl, float wh) {
    float lo = __builtin_bit_cast(float, u << 16);
    float hi = __builtin_bit_cast(float, u & 0xFFFF0000u);
    return lo * wl + hi * wh;
}

__device__ __forceinline__ float bdot16(uint4 u0, uint4 u1, float4 w0, float4 w1,
                                        float4 w2, float4 w3) {
    return bhalf2(u0.x, w0.x, w0.y) + bhalf2(u0.y, w0.z, w0.w) +
           bhalf2(u0.z, w1.x, w1.y) + bhalf2(u0.w, w1.z, w1.w) +
           bhalf2(u1.x, w2.x, w2.y) + bhalf2(u1.y, w2.z, w2.w) +
           bhalf2(u1.z, w3.x, w3.y) + bhalf2(u1.w, w3.z, w3.w);
}

__global__ __launch_bounds__(256) void aggregate_kernel(
    const float* __restrict__ h,
    const float* __restrict__ sumv, const float* __restrict__ sqv,
    const float* __restrict__ bnw, const float* __restrict__ bnb,
    int leaky,
    const int* __restrict__ off,
    const int* __restrict__ srcS,
    const unsigned* __restrict__ attrS,   // bf16-packed rows, 8 uints each
    const float* __restrict__ Wle, const float* __restrict__ ble,
    const float* __restrict__ epsArr, int layer,
    float* __restrict__ z) {
    const int d = threadIdx.x & 63;
    const int node = __builtin_amdgcn_readfirstlane(blockIdx.x * 4 + (threadIdx.x >> 6));

    float mean = sumv[d] / FN;
    float var = sqv[d] / FN - mean * mean;
    float cA = rsqrtf(var + BN_EPS) * bnw[d];
    float cB = bnb[d] - mean * cA;
    const float4* wp = (const float4*)(Wle + d * 16);
    float4 w0 = wp[0], w1 = wp[1], w2 = wp[2], w3 = wp[3];
    float be = ble[d];
    float epsv = 1.0f + epsArr[layer];

    int p0 = off[node], p1 = off[node + 1];  // uniform -> s_load
    float hv = h[(size_t)node * 64 + d];     // issue early

    float acc = 0.0f;
    for (int p = p0; p < p1; p += 8) {
        int idx[8];
        float g[8], e[8];
#pragma unroll
        for (int j = 0; j < 8; ++j) {
            int q = p + j;
            if (q > p1 - 1) q = p1 - 1;      // uniform clamp
            idx[j] = srcS[q];                // uniform -> s_load
        }
#pragma unroll
        for (int j = 0; j < 8; ++j)
            g[j] = h[(size_t)idx[j] * 64 + d];  // 8 vector gathers in flight
#pragma unroll
        for (int j = 0; j < 8; ++j) {
            int q = p + j;
            if (q > p1 - 1) q = p1 - 1;
            const uint4* ar = (const uint4*)(attrS + (size_t)q * 8);
            uint4 u0 = ar[0], u1 = ar[1];    // uniform -> s_load
            e[j] = bdot16(u0, u1, w0, w1, w2, w3) + be;
        }
#pragma unroll
        for (int j = 0; j < 8; ++j) {
            float gg = g[j] * cA + cB;
            if (leaky) gg = gg > 0.f ? gg : 0.01f * gg;
            float m = fmaxf(gg + e[j], 0.f);
            acc += (p + j < p1) ? m : 0.f;
        }
    }
    hv = hv * cA + cB;
    if (leaky) hv = hv > 0.f ? hv : 0.01f * hv;
    z[(size_t)node * 64 + d] = epsv * hv + acc;
}

// ---------------- MFMA bf16 GEMM: dst = f(src) @ W^T + bias [+resid] ----------------
// Block = 256 thr = 4 waves; block tile 64 rows x 64 cols; wave computes 16x64.
// A frag: A[m=lane&15][k=quad*8+j]; B frag: B[k=quad*8+j][n=lane&15] = W[n][k].
// Register-direct (no LDS staging). Weights pre-converted bf16 [col][64].

template <bool BN_IN, bool STATS, bool RESID>
__global__ __launch_bounds__(256) void gemm_mfma(
    const float* __restrict__ src, int src_ld,
    const unsigned short* __restrict__ Wb,   // bf16 [ncols][64]
    const float* __restrict__ bias,
    float* __restrict__ dst, int dst_ld,
    const float* __restrict__ resid,
    const float* __restrict__ statsInSum, const float* __restrict__ statsInSq,
    const float* __restrict__ bnw, const float* __restrict__ bnb,
    float* __restrict__ statsOutSum, float* __restrict__ statsOutSq) {
    __shared__ float cA[64], cB[64];
    __shared__ float sS[64], sQ[64];
    int tid = threadIdx.x;
    int r0 = blockIdx.x * 64;
    int c0 = blockIdx.y * 64;

    if (BN_IN && tid < 64) {
        float m = statsInSum[tid] / FN;
        float v = statsInSq[tid] / FN - m * m;
        float a = rsqrtf(v + BN_EPS) * bnw[tid];
        cA[tid] = a;
        cB[tid] = bnb[tid] - m * a;
    }
    if (STATS && tid < 64) { sS[tid] = 0.f; sQ[tid] = 0.f; }
    if (BN_IN || STATS) __syncthreads();

    int w = tid >> 6, lane = tid & 63;
    int n16 = lane & 15, quad = lane >> 4;
    int arow = r0 + w * 16 + n16;
    const float* asrc = src + (size_t)(arow < GN ? arow : 0) * src_ld + quad * 8;

    // A fragments (kk = 0,1 covering k 0..31, 32..63)
    bf16x8 afr[2];
#pragma unroll
    for (int kk = 0; kk < 2; ++kk) {
        const float4* p = (const float4*)(asrc + kk * 32);
        float4 x0 = p[0], x1 = p[1];
        float av[8] = {x0.x, x0.y, x0.z, x0.w, x1.x, x1.y, x1.z, x1.w};
        if (BN_IN) {
            int kb = quad * 8 + kk * 32;
#pragma unroll
            for (int j = 0; j < 8; ++j) {
                float t = av[j] * cA[kb + j] + cB[kb + j];
                av[j] = t > 0.f ? t : 0.01f * t;
            }
        }
        uint4 fu;
        fu.x = packbf2(av[0], av[1]); fu.y = packbf2(av[2], av[3]);
        fu.z = packbf2(av[4], av[5]); fu.w = packbf2(av[6], av[7]);
        afr[kk] = __builtin_bit_cast(bf16x8, fu);
    }

    // B fragments: 4 col tiles x 2 kk (weights already bf16)
    bf16x8 bfr[4][2];
#pragma unroll
    for (int t = 0; t < 4; ++t) {
        int col = c0 + t * 16 + n16;
        const unsigned short* bsrc = Wb + (size_t)col * 64 + quad * 8;
#pragma unroll
        for (int kk = 0; kk < 2; ++kk)
            bfr[t][kk] = *(const bf16x8*)(bsrc + kk * 32);
    }

    f32x4 acc[4] = {{0.f, 0.f, 0.f, 0.f}, {0.f, 0.f, 0.f, 0.f},
                    {0.f, 0.f, 0.f, 0.f}, {0.f, 0.f, 0.f, 0.f}};
#pragma unroll
    for (int t = 0; t < 4; ++t) {
        acc[t] = __builtin_amdgcn_mfma_f32_16x16x32_bf16(afr[0], bfr[t][0], acc[t], 0, 0, 0);
        acc[t] = __builtin_amdgcn_mfma_f32_16x16x32_bf16(afr[1], bfr[t][1], acc[t], 0, 0, 0);
    }

    // epilogue: D row = r0 + w*16 + quad*4 + reg, col = c0 + t*16 + n16
    float ls[4] = {0.f, 0.f, 0.f, 0.f}, lq[4] = {0.f, 0.f, 0.f, 0.f};
#pragma unroll
    for (int t = 0; t < 4; ++t) {
        int col = c0 + t * 16 + n16;
        float bv = bias[col];
#pragma unroll
        for (int r = 0; r < 4; ++r) {
            int row = r0 + w * 16 + quad * 4 + r;
            if (row < GN) {
                float o = acc[t][r] + bv;
                if (RESID) o += resid[(size_t)row * dst_ld + col];
                dst[(size_t)row * dst_ld + col] = o;
                if (STATS) { ls[t] += o; lq[t] += o * o; }
            }
        }
    }

    if (STATS) {
#pragma unroll
        for (int t = 0; t < 4; ++t) {
            float s = ls[t], q = lq[t];
            s += __shfl_down(s, 16, 64); s += __shfl_down(s, 32, 64);
            q += __shfl_down(q, 16, 64); q += __shfl_down(q, 32, 64);
            if (lane < 16) {
                atomicAdd(&sS[t * 16 + n16], s);
                atomicAdd(&sQ[t * 16 + n16], q);
            }
        }
        __syncthreads();
        if (tid < 64) {
            atomicAdd(&statsOutSum[c0 + tid], sS[tid]);
            atomicAdd(&statsOutSq[c0 + tid], sQ[tid]);
        }
    }
}

// ---------------- classifier tail ----------------

__global__ __launch_bounds__(256) void cls2_kernel(
    const float* __restrict__ y1,
    const float* __restrict__ sum, const float* __restrict__ sq,
    const float* __restrict__ bnw, const float* __restrict__ bnb,
    const float* __restrict__ w2, const float* __restrict__ b2,
    float* __restrict__ out) {
    int node = blockIdx.x * 4 + (threadIdx.x >> 6);
    int d = threadIdx.x & 63;
    if (node >= GN) return;
    float partial = 0.f;
#pragma unroll
    for (int hh = 0; hh < 2; ++hh) {
        int c = d + hh * 64;
        float m = sum[c] / FN;
        float var = sq[c] / FN - m * m;
        float a = rsqrtf(var + BN_EPS) * bnw[c];
        float v = y1[(size_t)node * 128 + c];
        v = v * a + (bnb[c] - m * a);
        v = v > 0.f ? v : 0.01f * v;
        partial += v * w2[c];
    }
    for (int o = 32; o >= 1; o >>= 1) partial += __shfl_down(partial, o, 64);
    if (d == 0) out[node] = partial + b2[0];
}

// ---------------- launcher ----------------

extern "C" void kernel_launch(void* const* d_in, const int* in_sizes, int n_in,
                              void* d_out, int out_size, void* d_ws, size_t ws_size,
                              hipStream_t stream) {
    (void)in_sizes; (void)n_in; (void)out_size; (void)ws_size;
    const float* x    = (const float*)d_in[0];
    const int*   ei   = (const int*)d_in[1];
    const float* attr = (const float*)d_in[2];
    const float* bnpw = (const float*)d_in[3];
    const float* bnpb = (const float*)d_in[4];
    const float* elw  = (const float*)d_in[5];
    const float* elb  = (const float*)d_in[6];
    const float* l1w  = (const float*)d_in[7];
    const float* l1b  = (const float*)d_in[8];
    const float* bnmw = (const float*)d_in[9];
    const float* bnmb = (const float*)d_in[10];
    const float* l2w  = (const float*)d_in[11];
    const float* l2b  = (const float*)d_in[12];
    const float* epsA = (const float*)d_in[13];
    const float* c1w  = (const float*)d_in[14];
    const float* c1b  = (const float*)d_in[15];
    const float* cbw  = (const float*)d_in[16];
    const float* cbb  = (const float*)d_in[17];
    const float* c2w  = (const float*)d_in[18];
    const float* c2b  = (const float*)d_in[19];
    const int* srcArr = ei;
    const int* dstArr = ei + GE;

    char* base = (char*)d_ws;
    size_t ofs = 0;
    auto alloc = [&](size_t bytes) {
        void* p = base + ofs;
        ofs = (ofs + bytes + 1023) & ~(size_t)1023;
        return p;
    };
    int* off           = (int*)alloc((size_t)(GN + 1) * 4);
    int* cursor        = (int*)alloc((size_t)GN * 4);      // doubles as deg
    int* src_sorted    = (int*)alloc((size_t)GE * 4);
    unsigned* attr_sorted = (unsigned*)alloc((size_t)GE * 32);  // bf16 rows, 32B each
    unsigned short* wbf = (unsigned short*)alloc(40960 * 2);
    int* bsum   = (int*)alloc(1024);
    int* bbase  = (int*)alloc(1024);
    float* stPre = (float*)alloc(512);
    float* stMid = (float*)alloc(512);
    float* stCls = (float*)alloc(1024);
    float* h = (float*)alloc((size_t)GN * 256);
    float* z = (float*)alloc((size_t)GN * 256);
    float* y1 = (float*)attr_sorted;  // GE*32 = 51.2MB == GN*128*4 exactly

    constexpr int NB = (GN + 1023) / 1024;  // 98

    // ---- CSR by dst, direct sorted-materialization (bf16 attr) ----
    hipMemsetAsync(cursor, 0, (size_t)GN * 4, stream);
    hist_kernel<<<2048, 256, 0, stream>>>(dstArr, cursor);
    bsum_kernel<<<NB, 256, 0, stream>>>(cursor, bsum);
    bscan_kernel<<<1, 64, 0, stream>>>(bsum, bbase, off + GN, NB);
    bscatter_kernel<<<NB, 256, 0, stream>>>(cursor, bbase, off);
    fill_sorted_kernel<<<2048, 256, 0, stream>>>(srcArr, dstArr, (const float4*)attr,
                                                 cursor, src_sorted, attr_sorted);
    convw_kernel<<<160, 256, 0, stream>>>(l1w, l2w, c1w, wbf);

    // ---- layer-0 pre-BN stats on x ----
    hipMemsetAsync(stPre, 0, 512, stream);
    col_stats64<<<512, 256, 0, stream>>>(x, stPre, stPre + 64);

    const float* hsrc = x;
    dim3 g1(1563, 1);
    for (int i = 0; i < 4; ++i) {
        aggregate_kernel<<<25000, 256, 0, stream>>>(
            hsrc, stPre, stPre + 64, bnpw + i * 64, bnpb + i * 64, (i > 0) ? 1 : 0,
            off, src_sorted, attr_sorted, elw + i * 1024, elb + i * 64, epsA, i, z);
        hipMemsetAsync(stMid, 0, 512, stream);
        gemm_mfma<false, true, false><<<g1, 256, 0, stream>>>(
            z, 64, wbf + i * 4096, l1b + i * 64, z, 64, nullptr,
            nullptr, nullptr, nullptr, nullptr, stMid, stMid + 64);
        hipMemsetAsync(stPre, 0, 512, stream);
        if (i == 0)
            gemm_mfma<true, true, false><<<g1, 256, 0, stream>>>(
                z, 64, wbf + 16384 + i * 4096, l2b + i * 64, h, 64, nullptr,
                stMid, stMid + 64, bnmw + i * 64, bnmb + i * 64, stPre, stPre + 64);
        else
            gemm_mfma<true, true, true><<<g1, 256, 0, stream>>>(
                z, 64, wbf + 16384 + i * 4096, l2b + i * 64, h, 64, h,
                stMid, stMid + 64, bnmw + i * 64, bnmb + i * 64, stPre, stPre + 64);
        hsrc = h;
    }

    // ---- classifier ----
    hipMemsetAsync(stCls, 0, 1024, stream);
    dim3 gc(1563, 2);
    gemm_mfma<false, true, false><<<gc, 256, 0, stream>>>(
        h, 64, wbf + 32768, c1b, y1, 128, nullptr,
        nullptr, nullptr, nullptr, nullptr, stCls, stCls + 128);
    cls2_kernel<<<25000, 256, 0, stream>>>(y1, stCls, stCls + 128, cbw, cbb, c2w, c2b,
                                           (float*)d_out);
}

// Round 5
// 1177.039 us; speedup vs baseline: 2.1298x; 1.2230x over previous
//
#include <hip/hip_runtime.h>
#include <hip/hip_bf16.h>

// Problem constants (fixed by reference)
constexpr int GN = 100000;   // nodes
constexpr int GE = 1600000;  // edges
constexpr float FN = 100000.0f;
constexpr float BN_EPS = 1e-5f;

typedef __attribute__((ext_vector_type(8))) short bf16x8;
typedef __attribute__((ext_vector_type(4))) float f32x4;

__device__ __forceinline__ unsigned packbf2(float a, float b) {
    __hip_bfloat162 h = __float22bfloat162_rn(float2{a, b});
    union { __hip_bfloat162 h2; unsigned u; } cv;
    cv.h2 = h;
    return cv.u;
}

__device__ __forceinline__ unsigned short bf16rn(float f) {
    unsigned u = __builtin_bit_cast(unsigned, f);
    unsigned r = (u + 0x7FFF + ((u >> 16) & 1)) >> 16;
    return (unsigned short)r;
}

__device__ __forceinline__ float bflo(unsigned u) {
    return __builtin_bit_cast(float, u << 16);
}
__device__ __forceinline__ float bfhi(unsigned u) {
    return __builtin_bit_cast(float, u & 0xFFFF0000u);
}

// ---------------- CSR build ----------------

__global__ __launch_bounds__(256) void hist_kernel(const int* __restrict__ dst,
                                                   int* __restrict__ deg) {
    for (int i = blockIdx.x * blockDim.x + threadIdx.x; i < GE; i += gridDim.x * blockDim.x)
        atomicAdd(&deg[dst[i]], 1);
}

// block sums for scan + folded weight conversion (saves a dispatch)
__global__ __launch_bounds__(256) void bsum_kernel(const int* __restrict__ deg,
                                                   int* __restrict__ bsum,
                                                   const float* __restrict__ l1w,
                                                   const float* __restrict__ l2w,
                                                   const float* __restrict__ c1w,
                                                   unsigned short* __restrict__ wb) {
    int b = blockIdx.x;
    int i0 = b * 1024 + threadIdx.x * 4;
    int s = 0;
#pragma unroll
    for (int k = 0; k < 4; ++k) {
        int i = i0 + k;
        if (i < GN) s += deg[i];
    }
    for (int o = 32; o >= 1; o >>= 1) s += __shfl_down(s, o, 64);
    __shared__ int ws[4];
    if ((threadIdx.x & 63) == 0) ws[threadIdx.x >> 6] = s;
    __syncthreads();
    if (threadIdx.x == 0) bsum[b] = ws[0] + ws[1] + ws[2] + ws[3];
    // weight conversion (40960 elems over 98*256 threads)
    for (int i = b * 256 + threadIdx.x; i < 40960; i += gridDim.x * 256) {
        float v;
        if (i < 16384) v = l1w[i];
        else if (i < 32768) v = l2w[i - 16384];
        else v = c1w[i - 32768];
        wb[i] = bf16rn(v);
    }
}

__global__ void bscan_kernel(const int* __restrict__ bsum, int* __restrict__ bbase,
                             int* __restrict__ offEnd, int nb) {
    int t = threadIdx.x;  // 64 threads, 1 wave
    int carry = 0;
    for (int base = 0; base < nb; base += 64) {
        int v = (base + t < nb) ? bsum[base + t] : 0;
        int incl = v;
        for (int o = 1; o < 64; o <<= 1) {
            int u = __shfl_up(incl, o, 64);
            if (t >= o) incl += u;
        }
        if (base + t < nb) bbase[base + t] = carry + incl - v;
        carry += __shfl(incl, 63, 64);
    }
    if (t == 0) offEnd[0] = carry;
}

// writes exclusive prefix to BOTH off[] and (in place) cursor[] (== deg array)
__global__ __launch_bounds__(256) void bscatter_kernel(int* __restrict__ deg,
                                                       const int* __restrict__ bbase,
                                                       int* __restrict__ off) {
    int b = blockIdx.x;
    int t = threadIdx.x;
    int i0 = b * 1024 + t * 4;
    int v[4];
    int s = 0;
#pragma unroll
    for (int k = 0; k < 4; ++k) {
        int i = i0 + k;
        v[k] = (i < GN) ? deg[i] : 0;
        s += v[k];
    }
    int incl = s;
    int lane = t & 63;
    for (int o = 1; o < 64; o <<= 1) {
        int u = __shfl_up(incl, o, 64);
        if (lane >= o) incl += u;
    }
    __shared__ int wsum[4];
    if (lane == 63) wsum[t >> 6] = incl;
    __syncthreads();
    int w = t >> 6;
    int wb = 0;
#pragma unroll
    for (int k = 0; k < 4; ++k)
        if (k < w) wb += wsum[k];
    int ex = bbase[b] + wb + incl - s;
#pragma unroll
    for (int k = 0; k < 4; ++k) {
        int i = i0 + k;
        if (i < GN) { off[i] = ex; deg[i] = ex; }
        ex += v[k];
    }
}

// counting-sort fill: writes src_sorted and bf16 attr_sorted directly.
// Also zeroes the layer-0 stats buffer (consumed+filled by next dispatches).
__global__ __launch_bounds__(256) void fill_sorted_kernel(
    const int* __restrict__ src, const int* __restrict__ dst,
    const float4* __restrict__ attr,
    int* __restrict__ cursor,
    int* __restrict__ srcS, unsigned* __restrict__ attrS,
    float* __restrict__ zeroBuf) {
    if (blockIdx.x == 0 && threadIdx.x < 128) zeroBuf[threadIdx.x] = 0.f;
    for (int i = blockIdx.x * blockDim.x + threadIdx.x; i < GE; i += gridDim.x * blockDim.x) {
        int pos = atomicAdd(&cursor[dst[i]], 1);
        srcS[pos] = src[i];
        size_t r = (size_t)i * 4;
        float4 a0 = attr[r], a1 = attr[r + 1], a2 = attr[r + 2], a3 = attr[r + 3];
        uint4 ua, ub;
        ua.x = packbf2(a0.x, a0.y); ua.y = packbf2(a0.z, a0.w);
        ua.z = packbf2(a1.x, a1.y); ua.w = packbf2(a1.z, a1.w);
        ub.x = packbf2(a2.x, a2.y); ub.y = packbf2(a2.z, a2.w);
        ub.z = packbf2(a3.x, a3.y); ub.w = packbf2(a3.z, a3.w);
        uint4* out = (uint4*)(attrS + (size_t)pos * 8);
        out[0] = ua;
        out[1] = ub;
    }
}

// ---------------- column stats on x (+ bf16 conversion of x) ----------------

__global__ __launch_bounds__(256) void col_stats64(const float* __restrict__ in,
                                                   float* __restrict__ sum,
                                                   float* __restrict__ sq,
                                                   unsigned short* __restrict__ outb) {
    int c = threadIdx.x & 63;
    int lr = threadIdx.x >> 6;
    float s = 0.f, q = 0.f;
    for (int r = blockIdx.x * 4 + lr; r < GN; r += gridDim.x * 4) {
        float v = in[(size_t)r * 64 + c];
        s += v;
        q += v * v;
        outb[(size_t)r * 64 + c] = bf16rn(v);
    }
    __shared__ float S[256];
    S[threadIdx.x] = s;
    __syncthreads();
    if (threadIdx.x < 64) {
        float a = S[threadIdx.x] + S[threadIdx.x + 64] + S[threadIdx.x + 128] + S[threadIdx.x + 192];
        atomicAdd(&sum[threadIdx.x], a);
    }
    __syncthreads();
    S[threadIdx.x] = q;
    __syncthreads();
    if (threadIdx.x < 64) {
        float a = S[threadIdx.x] + S[threadIdx.x + 64] + S[threadIdx.x + 128] + S[threadIdx.x + 192];
        atomicAdd(&sq[threadIdx.x], a);
    }
}

// ---------------- fused BN(pre) + GINE aggregation, scalar-path ----------------
// One wave per node (lane = feature). Uniform (scalar) loads for src ids and
// attr rows; attr bf16 decode on uniform values -> SALU; VALU does 16 fma/edge.
// Gathers from bf16 feature copy (halves gather line traffic).

__device__ __forceinline__ float edot8s(uint4 a, uint4 b, const float* __restrict__ w,
                                        float be) {
    float e = be;
    e = fmaf(bflo(a.x), w[0], e);  e = fmaf(bfhi(a.x), w[1], e);
    e = fmaf(bflo(a.y), w[2], e);  e = fmaf(bfhi(a.y), w[3], e);
    e = fmaf(bflo(a.z), w[4], e);  e = fmaf(bfhi(a.z), w[5], e);
    e = fmaf(bflo(a.w), w[6], e);  e = fmaf(bfhi(a.w), w[7], e);
    e = fmaf(bflo(b.x), w[8], e);  e = fmaf(bfhi(b.x), w[9], e);
    e = fmaf(bflo(b.y), w[10], e); e = fmaf(bfhi(b.y), w[11], e);
    e = fmaf(bflo(b.z), w[12], e); e = fmaf(bfhi(b.z), w[13], e);
    e = fmaf(bflo(b.w), w[14], e); e = fmaf(bfhi(b.w), w[15], e);
    return e;
}

__global__ __launch_bounds__(256) void aggregate_kernel(
    const float* __restrict__ h,            // fp32 features (self term)
    const unsigned short* __restrict__ hb,  // bf16 features (gather)
    const float* __restrict__ sumv, const float* __restrict__ sqv,
    const float* __restrict__ bnw, const float* __restrict__ bnb,
    int leaky,
    const int* __restrict__ off,
    const int* __restrict__ srcS,
    const unsigned* __restrict__ attrS,     // bf16-packed rows, 8 uints each
    const float* __restrict__ Wle, const float* __restrict__ ble,
    const float* __restrict__ epsArr, int layer,
    float* __restrict__ z, float* __restrict__ zeroBuf) {
    if (blockIdx.x == 0 && threadIdx.x < 128) zeroBuf[threadIdx.x] = 0.f;
    const int d = threadIdx.x & 63;
    const int node = __builtin_amdgcn_readfirstlane(blockIdx.x * 4 + (threadIdx.x >> 6));

    float mean = sumv[d] / FN;
    float var = sqv[d] / FN - mean * mean;
    float cA = rsqrtf(var + BN_EPS) * bnw[d];
    float cB = bnb[d] - mean * cA;
    float w[16];
#pragma unroll
    for (int k = 0; k < 16; k += 4) {
        float4 t = *(const float4*)(Wle + d * 16 + k);
        w[k] = t.x; w[k + 1] = t.y; w[k + 2] = t.z; w[k + 3] = t.w;
    }
    float be = ble[d];
    float epsv = 1.0f + epsArr[layer];

    int p0 = off[node], p1 = off[node + 1];  // uniform -> s_load
    float hv = h[(size_t)node * 64 + d];     // issue early

    float acc = 0.0f;
    int p = p0;
    int pfull = p0 + ((p1 - p0) & ~7);
    for (; p < pfull; p += 8) {              // full groups: no masking at all
        int idx[8];
#pragma unroll
        for (int j = 0; j < 8; ++j) idx[j] = srcS[p + j];  // s_load (contiguous)
        float g[8];
#pragma unroll
        for (int j = 0; j < 8; ++j)
            g[j] = bflo(hb[(size_t)idx[j] * 64 + d]);      // 8 gathers in flight
#pragma unroll
        for (int j = 0; j < 8; ++j) {
            const uint4* ar = (const uint4*)(attrS + (size_t)(p + j) * 8);
            float e = edot8s(ar[0], ar[1], w, be);
            float gg = g[j] * cA + cB;
            if (leaky) gg = fmaxf(gg, 0.01f * gg);
            acc += fmaxf(gg + e, 0.f);
        }
    }
    if (p < p1) {                            // single masked tail group
        int idx[8];
#pragma unroll
        for (int j = 0; j < 8; ++j) {
            int q = p + j;
            if (q > p1 - 1) q = p1 - 1;
            idx[j] = srcS[q];
        }
        float g[8];
#pragma unroll
        for (int j = 0; j < 8; ++j)
            g[j] = bflo(hb[(size_t)idx[j] * 64 + d]);
#pragma unroll
        for (int j = 0; j < 8; ++j) {
            int q = p + j;
            if (q > p1 - 1) q = p1 - 1;
            const uint4* ar = (const uint4*)(attrS + (size_t)q * 8);
            float e = edot8s(ar[0], ar[1], w, be);
            float gg = g[j] * cA + cB;
            if (leaky) gg = fmaxf(gg, 0.01f * gg);
            float m = fmaxf(gg + e, 0.f);
            acc += (p + j < p1) ? m : 0.f;
        }
    }
    hv = hv * cA + cB;
    if (leaky) hv = fmaxf(hv, 0.01f * hv);
    z[(size_t)node * 64 + d] = epsv * hv + acc;
}

// ---------------- MFMA bf16 GEMM: dst = f(src) @ W^T + bias [+resid] ----------------
// Block = 256 thr = 4 waves; tile 64 rows x 64 cols; grid-stride over row tiles
// (B-fragments + stats flush amortized). Optional bf16 secondary output.

template <bool BN_IN, bool STATS, bool RESID, bool BF16OUT>
__global__ __launch_bounds__(256) void gemm_mfma(
    const float* __restrict__ src, int src_ld,
    const unsigned short* __restrict__ Wb,   // bf16 [ncols][64]
    const float* __restrict__ bias,
    float* __restrict__ dst, int dst_ld,
    unsigned short* __restrict__ dstb,       // bf16 copy out (ld 64)
    const float* __restrict__ resid,
    const float* __restrict__ statsInSum, const float* __restrict__ statsInSq,
    const float* __restrict__ bnw, const float* __restrict__ bnb,
    float* __restrict__ statsOutSum, float* __restrict__ statsOutSq,
    float* __restrict__ zeroBuf, int zeroN) {
    __shared__ float cA[64], cB[64];
    __shared__ float sS[64], sQ[64];
    int tid = threadIdx.x;
    if (zeroBuf && blockIdx.x == 0 && blockIdx.y == 0 && tid < zeroN) zeroBuf[tid] = 0.f;
    int c0 = blockIdx.y * 64;

    if (BN_IN) {
        if (tid < 64) {
            float m = statsInSum[tid] / FN;
            float v = statsInSq[tid] / FN - m * m;
            float a = rsqrtf(v + BN_EPS) * bnw[tid];
            cA[tid] = a;
            cB[tid] = bnb[tid] - m * a;
        }
        __syncthreads();
    }

    int w = tid >> 6, lane = tid & 63;
    int n16 = lane & 15, quad = lane >> 4;

    // B fragments once per block
    bf16x8 bfr[4][2];
#pragma unroll
    for (int t = 0; t < 4; ++t) {
        int col = c0 + t * 16 + n16;
        const unsigned short* bsrc = Wb + (size_t)col * 64 + quad * 8;
#pragma unroll
        for (int kk = 0; kk < 2; ++kk)
            bfr[t][kk] = *(const bf16x8*)(bsrc + kk * 32);
    }

    float ls[4] = {0.f, 0.f, 0.f, 0.f}, lq[4] = {0.f, 0.f, 0.f, 0.f};
    constexpr int NT = (GN + 63) / 64;  // 1563
    for (int tile = blockIdx.x; tile < NT; tile += gridDim.x) {
        int r0 = tile * 64;
        int arow = r0 + w * 16 + n16;
        const float* asrc = src + (size_t)(arow < GN ? arow : 0) * src_ld + quad * 8;

        bf16x8 afr[2];
#pragma unroll
        for (int kk = 0; kk < 2; ++kk) {
            const float4* p = (const float4*)(asrc + kk * 32);
            float4 x0 = p[0], x1 = p[1];
            float av[8] = {x0.x, x0.y, x0.z, x0.w, x1.x, x1.y, x1.z, x1.w};
            if (BN_IN) {
                int kb = quad * 8 + kk * 32;
#pragma unroll
                for (int j = 0; j < 8; ++j) {
                    float t = av[j] * cA[kb + j] + cB[kb + j];
                    av[j] = fmaxf(t, 0.01f * t);
                }
            }
            uint4 fu;
            fu.x = packbf2(av[0], av[1]); fu.y = packbf2(av[2], av[3]);
            fu.z = packbf2(av[4], av[5]); fu.w = packbf2(av[6], av[7]);
            afr[kk] = __builtin_bit_cast(bf16x8, fu);
        }

        f32x4 acc[4] = {{0.f, 0.f, 0.f, 0.f}, {0.f, 0.f, 0.f, 0.f},
                        {0.f, 0.f, 0.f, 0.f}, {0.f, 0.f, 0.f, 0.f}};
#pragma unroll
        for (int t = 0; t < 4; ++t) {
            acc[t] = __builtin_amdgcn_mfma_f32_16x16x32_bf16(afr[0], bfr[t][0], acc[t], 0, 0, 0);
            acc[t] = __builtin_amdgcn_mfma_f32_16x16x32_bf16(afr[1], bfr[t][1], acc[t], 0, 0, 0);
        }

        // epilogue: D row = r0 + w*16 + quad*4 + r, col = c0 + t*16 + n16
#pragma unroll
        for (int t = 0; t < 4; ++t) {
            int col = c0 + t * 16 + n16;
            float bv = bias[col];
#pragma unroll
            for (int r = 0; r < 4; ++r) {
                int row = r0 + w * 16 + quad * 4 + r;
                if (row < GN) {
                    float o = acc[t][r] + bv;
                    if (RESID) o += resid[(size_t)row * dst_ld + col];
                    dst[(size_t)row * dst_ld + col] = o;
                    if (BF16OUT) dstb[(size_t)row * 64 + col] = bf16rn(o);
                    if (STATS) { ls[t] += o; lq[t] += o * o; }
                }
            }
        }
    }

    if (STATS) {
        if (tid < 64) { sS[tid] = 0.f; sQ[tid] = 0.f; }
        __syncthreads();
#pragma unroll
        for (int t = 0; t < 4; ++t) {
            float s = ls[t], q = lq[t];
            s += __shfl_down(s, 16, 64); s += __shfl_down(s, 32, 64);
            q += __shfl_down(q, 16, 64); q += __shfl_down(q, 32, 64);
            if (lane < 16) {
                atomicAdd(&sS[t * 16 + n16], s);
                atomicAdd(&sQ[t * 16 + n16], q);
            }
        }
        __syncthreads();
        if (tid < 64) {
            atomicAdd(&statsOutSum[c0 + tid], sS[tid]);
            atomicAdd(&statsOutSq[c0 + tid], sQ[tid]);
        }
    }
}

// ---------------- classifier tail ----------------

__global__ __launch_bounds__(256) void cls2_kernel(
    const float* __restrict__ y1,
    const float* __restrict__ sum, const float* __restrict__ sq,
    const float* __restrict__ bnw, const float* __restrict__ bnb,
    const float* __restrict__ w2, const float* __restrict__ b2,
    float* __restrict__ out) {
    int node = blockIdx.x * 4 + (threadIdx.x >> 6);
    int d = threadIdx.x & 63;
    if (node >= GN) return;
    float partial = 0.f;
#pragma unroll
    for (int hh = 0; hh < 2; ++hh) {
        int c = d + hh * 64;
        float m = sum[c] / FN;
        float var = sq[c] / FN - m * m;
        float a = rsqrtf(var + BN_EPS) * bnw[c];
        float v = y1[(size_t)node * 128 + c];
        v = v * a + (bnb[c] - m * a);
        v = fmaxf(v, 0.01f * v);
        partial += v * w2[c];
    }
    for (int o = 32; o >= 1; o >>= 1) partial += __shfl_down(partial, o, 64);
    if (d == 0) out[node] = partial + b2[0];
}

// ---------------- launcher ----------------

extern "C" void kernel_launch(void* const* d_in, const int* in_sizes, int n_in,
                              void* d_out, int out_size, void* d_ws, size_t ws_size,
                              hipStream_t stream) {
    (void)in_sizes; (void)n_in; (void)out_size; (void)ws_size;
    const float* x    = (const float*)d_in[0];
    const int*   ei   = (const int*)d_in[1];
    const float* attr = (const float*)d_in[2];
    const float* bnpw = (const float*)d_in[3];
    const float* bnpb = (const float*)d_in[4];
    const float* elw  = (const float*)d_in[5];
    const float* elb  = (const float*)d_in[6];
    const float* l1w  = (const float*)d_in[7];
    const float* l1b  = (const float*)d_in[8];
    const float* bnmw = (const float*)d_in[9];
    const float* bnmb = (const float*)d_in[10];
    const float* l2w  = (const float*)d_in[11];
    const float* l2b  = (const float*)d_in[12];
    const float* epsA = (const float*)d_in[13];
    const float* c1w  = (const float*)d_in[14];
    const float* c1b  = (const float*)d_in[15];
    const float* cbw  = (const float*)d_in[16];
    const float* cbb  = (const float*)d_in[17];
    const float* c2w  = (const float*)d_in[18];
    const float* c2b  = (const float*)d_in[19];
    const int* srcArr = ei;
    const int* dstArr = ei + GE;

    char* base = (char*)d_ws;
    size_t ofs = 0;
    auto alloc = [&](size_t bytes) {
        void* p = base + ofs;
        ofs = (ofs + bytes + 1023) & ~(size_t)1023;
        return p;
    };
    int* off              = (int*)alloc((size_t)(GN + 1) * 4);
    int* cursor           = (int*)alloc((size_t)GN * 4);        // doubles as deg
    int* src_sorted       = (int*)alloc((size_t)GE * 4);
    unsigned* attr_sorted = (unsigned*)alloc((size_t)GE * 32);  // bf16 rows, 32B
    unsigned short* wbf   = (unsigned short*)alloc(40960 * 2);
    int* bsum   = (int*)alloc(1024);
    int* bbase  = (int*)alloc(1024);
    float* stP0 = (float*)alloc(512);
    float* stP1 = (float*)alloc(512);
    float* stM  = (float*)alloc(512);
    float* stC  = (float*)alloc(1024);
    float* h = (float*)alloc((size_t)GN * 256);
    float* z = (float*)alloc((size_t)GN * 256);
    unsigned short* xb = (unsigned short*)alloc((size_t)GN * 128);
    unsigned short* hb = (unsigned short*)alloc((size_t)GN * 128);
    float* y1 = (float*)attr_sorted;  // GE*32 = 51.2MB == GN*128*4 exactly

    constexpr int NB = (GN + 1023) / 1024;  // 98
    float* stP[2] = {stP0, stP1};

    // ---- CSR by dst + sorted materialization (bf16 attr) ----
    hipMemsetAsync(cursor, 0, (size_t)GN * 4, stream);
    hist_kernel<<<2048, 256, 0, stream>>>(dstArr, cursor);
    bsum_kernel<<<NB, 256, 0, stream>>>(cursor, bsum, l1w, l2w, c1w, wbf);
    bscan_kernel<<<1, 64, 0, stream>>>(bsum, bbase, off + GN, NB);
    bscatter_kernel<<<NB, 256, 0, stream>>>(cursor, bbase, off);
    fill_sorted_kernel<<<2048, 256, 0, stream>>>(srcArr, dstArr, (const float4*)attr,
                                                 cursor, src_sorted, attr_sorted, stP0);

    // ---- layer-0 pre-BN stats on x (+ x -> bf16) ----
    col_stats64<<<512, 256, 0, stream>>>(x, stP0, stP0 + 64, xb);

    const float* hsrc = x;
    const unsigned short* hbsrc = xb;
    dim3 gg(782, 1);
    for (int i = 0; i < 4; ++i) {
        float* sIn = stP[i & 1];
        float* sNext = stP[(i + 1) & 1];
        aggregate_kernel<<<25000, 256, 0, stream>>>(
            hsrc, hbsrc, sIn, sIn + 64, bnpw + i * 64, bnpb + i * 64, (i > 0) ? 1 : 0,
            off, src_sorted, attr_sorted, elw + i * 1024, elb + i * 64, epsA, i,
            z, stM);
        // gemm1: z = z @ l1w^T + b ; stats -> stM ; zero next-pre (or stC last layer)
        gemm_mfma<false, true, false, false><<<gg, 256, 0, stream>>>(
            z, 64, wbf + i * 4096, l1b + i * 64, z, 64, nullptr, nullptr,
            nullptr, nullptr, nullptr, nullptr, stM, stM + 64,
            (i == 3) ? stC : sNext, (i == 3) ? 256 : 128);
        // gemm2: h = leaky(bn(z)) @ l2w^T + b [+h] ; stats -> sNext ; bf16 copy
        if (i == 0)
            gemm_mfma<true, true, false, true><<<gg, 256, 0, stream>>>(
                z, 64, wbf + 16384 + i * 4096, l2b + i * 64, h, 64, hb, nullptr,
                stM, stM + 64, bnmw + i * 64, bnmb + i * 64, sNext, sNext + 64,
                nullptr, 0);
        else if (i < 3)
            gemm_mfma<true, true, true, true><<<gg, 256, 0, stream>>>(
                z, 64, wbf + 16384 + i * 4096, l2b + i * 64, h, 64, hb, h,
                stM, stM + 64, bnmw + i * 64, bnmb + i * 64, sNext, sNext + 64,
                nullptr, 0);
        else
            gemm_mfma<true, false, true, false><<<gg, 256, 0, stream>>>(
                z, 64, wbf + 16384 + i * 4096, l2b + i * 64, h, 64, nullptr, h,
                stM, stM + 64, bnmw + i * 64, bnmb + i * 64, nullptr, nullptr,
                nullptr, 0);
        hsrc = h;
        hbsrc = hb;
    }

    // ---- classifier ----
    dim3 gc(391, 2);
    gemm_mfma<false, true, false, false><<<gc, 256, 0, stream>>>(
        h, 64, wbf + 32768, c1b, y1, 128, nullptr, nullptr,
        nullptr, nullptr, nullptr, nullptr, stC, stC + 128, nullptr, 0);
    cls2_kernel<<<25000, 256, 0, stream>>>(y1, stC, stC + 128, cbw, cbb, c2w, c2b,
                                           (float*)d_out);
}

// Round 6
// 1004.095 us; speedup vs baseline: 2.4966x; 1.1722x over previous
//
#include <hip/hip_runtime.h>
#include <hip/hip_bf16.h>

// Problem constants (fixed by reference)
constexpr int GN = 100000;   // nodes
constexpr int GE = 1600000;  // edges
constexpr float FN = 100000.0f;
constexpr float BN_EPS = 1e-5f;

typedef __attribute__((ext_vector_type(8))) short bf16x8;
typedef __attribute__((ext_vector_type(4))) float f32x4;
typedef __bf16 bfp2 __attribute__((ext_vector_type(2)));

#if __has_builtin(__builtin_amdgcn_fdot2_f32_bf16)
#define HAVE_DOT2 1
#else
#define HAVE_DOT2 0
#endif

__device__ __forceinline__ unsigned packbf2(float a, float b) {
    __hip_bfloat162 h = __float22bfloat162_rn(float2{a, b});
    union { __hip_bfloat162 h2; unsigned u; } cv;
    cv.h2 = h;
    return cv.u;
}

__device__ __forceinline__ unsigned short bf16rn(float f) {
    unsigned u = __builtin_bit_cast(unsigned, f);
    unsigned r = (u + 0x7FFF + ((u >> 16) & 1)) >> 16;
    return (unsigned short)r;
}

__device__ __forceinline__ float bflo(unsigned u) {
    return __builtin_bit_cast(float, u << 16);
}
__device__ __forceinline__ float bfhi(unsigned u) {
    return __builtin_bit_cast(float, u & 0xFFFF0000u);
}
__device__ __forceinline__ float bfu16(unsigned short u) {
    return __builtin_bit_cast(float, (unsigned)u << 16);
}

// ---------------- CSR build ----------------

__global__ __launch_bounds__(256) void hist_kernel(const int* __restrict__ dst,
                                                   int* __restrict__ deg) {
    for (int i = blockIdx.x * blockDim.x + threadIdx.x; i < GE; i += gridDim.x * blockDim.x)
        atomicAdd(&deg[dst[i]], 1);
}

// block sums for scan + folded weight conversion (saves a dispatch)
__global__ __launch_bounds__(256) void bsum_kernel(const int* __restrict__ deg,
                                                   int* __restrict__ bsum,
                                                   const float* __restrict__ l1w,
                                                   const float* __restrict__ l2w,
                                                   const float* __restrict__ c1w,
                                                   unsigned short* __restrict__ wb) {
    int b = blockIdx.x;
    int i0 = b * 1024 + threadIdx.x * 4;
    int s = 0;
#pragma unroll
    for (int k = 0; k < 4; ++k) {
        int i = i0 + k;
        if (i < GN) s += deg[i];
    }
    for (int o = 32; o >= 1; o >>= 1) s += __shfl_down(s, o, 64);
    __shared__ int ws[4];
    if ((threadIdx.x & 63) == 0) ws[threadIdx.x >> 6] = s;
    __syncthreads();
    if (threadIdx.x == 0) bsum[b] = ws[0] + ws[1] + ws[2] + ws[3];
    for (int i = b * 256 + threadIdx.x; i < 40960; i += gridDim.x * 256) {
        float v;
        if (i < 16384) v = l1w[i];
        else if (i < 32768) v = l2w[i - 16384];
        else v = c1w[i - 32768];
        wb[i] = bf16rn(v);
    }
}

__global__ void bscan_kernel(const int* __restrict__ bsum, int* __restrict__ bbase,
                             int* __restrict__ offEnd, int nb) {
    int t = threadIdx.x;  // 64 threads, 1 wave
    int carry = 0;
    for (int base = 0; base < nb; base += 64) {
        int v = (base + t < nb) ? bsum[base + t] : 0;
        int incl = v;
        for (int o = 1; o < 64; o <<= 1) {
            int u = __shfl_up(incl, o, 64);
            if (t >= o) incl += u;
        }
        if (base + t < nb) bbase[base + t] = carry + incl - v;
        carry += __shfl(incl, 63, 64);
    }
    if (t == 0) offEnd[0] = carry;
}

// writes exclusive prefix to BOTH off[] and (in place) cursor[] (== deg array)
__global__ __launch_bounds__(256) void bscatter_kernel(int* __restrict__ deg,
                                                       const int* __restrict__ bbase,
                                                       int* __restrict__ off) {
    int b = blockIdx.x;
    int t = threadIdx.x;
    int i0 = b * 1024 + t * 4;
    int v[4];
    int s = 0;
#pragma unroll
    for (int k = 0; k < 4; ++k) {
        int i = i0 + k;
        v[k] = (i < GN) ? deg[i] : 0;
        s += v[k];
    }
    int incl = s;
    int lane = t & 63;
    for (int o = 1; o < 64; o <<= 1) {
        int u = __shfl_up(incl, o, 64);
        if (lane >= o) incl += u;
    }
    __shared__ int wsum[4];
    if (lane == 63) wsum[t >> 6] = incl;
    __syncthreads();
    int w = t >> 6;
    int wb = 0;
#pragma unroll
    for (int k = 0; k < 4; ++k)
        if (k < w) wb += wsum[k];
    int ex = bbase[b] + wb + incl - s;
#pragma unroll
    for (int k = 0; k < 4; ++k) {
        int i = i0 + k;
        if (i < GN) { off[i] = ex; deg[i] = ex; }
        ex += v[k];
    }
}

// counting-sort fill: writes src_sorted and bf16 attr_sorted directly.
// Also zeroes the layer-0 stats buffer.
__global__ __launch_bounds__(256) void fill_sorted_kernel(
    const int* __restrict__ src, const int* __restrict__ dst,
    const float4* __restrict__ attr,
    int* __restrict__ cursor,
    int* __restrict__ srcS, unsigned* __restrict__ attrS,
    float* __restrict__ zeroBuf) {
    if (blockIdx.x == 0 && threadIdx.x < 128) zeroBuf[threadIdx.x] = 0.f;
    for (int i = blockIdx.x * blockDim.x + threadIdx.x; i < GE; i += gridDim.x * blockDim.x) {
        int pos = atomicAdd(&cursor[dst[i]], 1);
        srcS[pos] = src[i];
        size_t r = (size_t)i * 4;
        float4 a0 = attr[r], a1 = attr[r + 1], a2 = attr[r + 2], a3 = attr[r + 3];
        uint4 ua, ub;
        ua.x = packbf2(a0.x, a0.y); ua.y = packbf2(a0.z, a0.w);
        ua.z = packbf2(a1.x, a1.y); ua.w = packbf2(a1.z, a1.w);
        ub.x = packbf2(a2.x, a2.y); ub.y = packbf2(a2.z, a2.w);
        ub.z = packbf2(a3.x, a3.y); ub.w = packbf2(a3.z, a3.w);
        uint4* out = (uint4*)(attrS + (size_t)pos * 8);
        out[0] = ua;
        out[1] = ub;
    }
}

// ---------------- column stats on x (+ bf16 conversion of x) ----------------

__global__ __launch_bounds__(256) void col_stats64(const float* __restrict__ in,
                                                   float* __restrict__ sum,
                                                   float* __restrict__ sq,
                                                   unsigned short* __restrict__ outb) {
    int c = threadIdx.x & 63;
    int lr = threadIdx.x >> 6;
    float s = 0.f, q = 0.f;
    for (int r = blockIdx.x * 4 + lr; r < GN; r += gridDim.x * 4) {
        float v = in[(size_t)r * 64 + c];
        s += v;
        q += v * v;
        outb[(size_t)r * 64 + c] = bf16rn(v);
    }
    __shared__ float S[256];
    S[threadIdx.x] = s;
    __syncthreads();
    if (threadIdx.x < 64) {
        float a = S[threadIdx.x] + S[threadIdx.x + 64] + S[threadIdx.x + 128] + S[threadIdx.x + 192];
        atomicAdd(&sum[threadIdx.x], a);
    }
    __syncthreads();
    S[threadIdx.x] = q;
    __syncthreads();
    if (threadIdx.x < 64) {
        float a = S[threadIdx.x] + S[threadIdx.x + 64] + S[threadIdx.x + 128] + S[threadIdx.x + 192];
        atomicAdd(&sq[threadIdx.x], a);
    }
}

// ---------------- fused BN(pre) + GINE aggregation ----------------
// One wave per node (lane = feature). Uniform s_loads for src ids / attr rows;
// edge-linear via v_dot2_f32_bf16 (8 VALU/edge, no decode). bf16 gathers.

#if HAVE_DOT2
__device__ __forceinline__ float edot(uint4 a, uint4 b, const bfp2* __restrict__ wq,
                                      float e) {
    e = __builtin_amdgcn_fdot2_f32_bf16(__builtin_bit_cast(bfp2, a.x), wq[0], e, false);
    e = __builtin_amdgcn_fdot2_f32_bf16(__builtin_bit_cast(bfp2, a.y), wq[1], e, false);
    e = __builtin_amdgcn_fdot2_f32_bf16(__builtin_bit_cast(bfp2, a.z), wq[2], e, false);
    e = __builtin_amdgcn_fdot2_f32_bf16(__builtin_bit_cast(bfp2, a.w), wq[3], e, false);
    e = __builtin_amdgcn_fdot2_f32_bf16(__builtin_bit_cast(bfp2, b.x), wq[4], e, false);
    e = __builtin_amdgcn_fdot2_f32_bf16(__builtin_bit_cast(bfp2, b.y), wq[5], e, false);
    e = __builtin_amdgcn_fdot2_f32_bf16(__builtin_bit_cast(bfp2, b.z), wq[6], e, false);
    e = __builtin_amdgcn_fdot2_f32_bf16(__builtin_bit_cast(bfp2, b.w), wq[7], e, false);
    return e;
}
#else
__device__ __forceinline__ float edot(uint4 a, uint4 b, const float* __restrict__ w,
                                      float e) {
    e = fmaf(bflo(a.x), w[0], e);  e = fmaf(bfhi(a.x), w[1], e);
    e = fmaf(bflo(a.y), w[2], e);  e = fmaf(bfhi(a.y), w[3], e);
    e = fmaf(bflo(a.z), w[4], e);  e = fmaf(bfhi(a.z), w[5], e);
    e = fmaf(bflo(a.w), w[6], e);  e = fmaf(bfhi(a.w), w[7], e);
    e = fmaf(bflo(b.x), w[8], e);  e = fmaf(bfhi(b.x), w[9], e);
    e = fmaf(bflo(b.y), w[10], e); e = fmaf(bfhi(b.y), w[11], e);
    e = fmaf(bflo(b.z), w[12], e); e = fmaf(bfhi(b.z), w[13], e);
    e = fmaf(bflo(b.w), w[14], e); e = fmaf(bfhi(b.w), w[15], e);
    return e;
}
#endif

__global__ __launch_bounds__(256) void aggregate_kernel(
    const float* __restrict__ h,            // fp32 features (self term)
    const unsigned short* __restrict__ hb,  // bf16 features (gather)
    const float* __restrict__ sumv, const float* __restrict__ sqv,
    const float* __restrict__ bnw, const float* __restrict__ bnb,
    int leaky,
    const int* __restrict__ off,
    const int* __restrict__ srcS,
    const unsigned* __restrict__ attrS,     // bf16-packed rows, 8 uints each
    const float* __restrict__ Wle, const float* __restrict__ ble,
    const float* __restrict__ epsArr, int layer,
    unsigned short* __restrict__ zb,        // bf16 output (gemm1 input)
    float* __restrict__ zeroBuf) {
    if (blockIdx.x == 0 && threadIdx.x < 128) zeroBuf[threadIdx.x] = 0.f;
    const int d = threadIdx.x & 63;
    const int node = __builtin_amdgcn_readfirstlane(blockIdx.x * 4 + (threadIdx.x >> 6));

    float mean = sumv[d] / FN;
    float var = sqv[d] / FN - mean * mean;
    float cA = rsqrtf(var + BN_EPS) * bnw[d];
    float cB = bnb[d] - mean * cA;

#if HAVE_DOT2
    bfp2 wq[8];
#pragma unroll
    for (int k = 0; k < 8; ++k) {
        float2 t = *(const float2*)(Wle + d * 16 + k * 2);
        bfp2 v = {(__bf16)t.x, (__bf16)t.y};
        wq[k] = v;
    }
#else
    float wq[16];
#pragma unroll
    for (int k = 0; k < 16; k += 4) {
        float4 t = *(const float4*)(Wle + d * 16 + k);
        wq[k] = t.x; wq[k + 1] = t.y; wq[k + 2] = t.z; wq[k + 3] = t.w;
    }
#endif
    float be = ble[d];
    float epsv = 1.0f + epsArr[layer];

    int p0 = off[node], p1 = off[node + 1];  // uniform -> s_load
    float hv = h[(size_t)node * 64 + d];     // issue early

    float acc = 0.0f;
    int p = p0;
    int pfull = p0 + ((p1 - p0) & ~7);
    for (; p < pfull; p += 8) {              // full groups: no masking
        int idx[8];
#pragma unroll
        for (int j = 0; j < 8; ++j) idx[j] = srcS[p + j];  // s_load (contiguous)
        float g[8];
#pragma unroll
        for (int j = 0; j < 8; ++j)
            g[j] = bfu16(hb[(((unsigned)idx[j]) << 6) + d]);  // 32-bit offset gathers
#pragma unroll
        for (int j = 0; j < 8; ++j) {
            const uint4* ar = (const uint4*)(attrS + (size_t)(p + j) * 8);
            float e = edot(ar[0], ar[1], wq, be);
            float gg = g[j] * cA + cB;
            if (leaky) gg = fmaxf(gg, 0.01f * gg);
            acc += fmaxf(gg + e, 0.f);
        }
    }
    for (; p < p1; p += 4) {                 // masked tail, groups of 4
        int idx[4];
#pragma unroll
        for (int j = 0; j < 4; ++j) {
            int q = p + j;
            if (q > p1 - 1) q = p1 - 1;
            idx[j] = srcS[q];
        }
        float g[4];
#pragma unroll
        for (int j = 0; j < 4; ++j)
            g[j] = bfu16(hb[(((unsigned)idx[j]) << 6) + d]);
#pragma unroll
        for (int j = 0; j < 4; ++j) {
            int q = p + j;
            if (q > p1 - 1) q = p1 - 1;
            const uint4* ar = (const uint4*)(attrS + (size_t)q * 8);
            float e = edot(ar[0], ar[1], wq, be);
            float gg = g[j] * cA + cB;
            if (leaky) gg = fmaxf(gg, 0.01f * gg);
            float m = fmaxf(gg + e, 0.f);
            acc += (p + j < p1) ? m : 0.f;
        }
    }
    hv = hv * cA + cB;
    if (leaky) hv = fmaxf(hv, 0.01f * hv);
    zb[(size_t)node * 64 + d] = bf16rn(epsv * hv + acc);
}

// ---------------- MFMA bf16 GEMM: dst = f(src) @ W^T + bias [+resid] ----------------
// Block = 256 thr = 4 waves; tile 64 rows x 64 cols; grid-stride over row tiles.

template <bool BN_IN, bool ABF16, bool STATS, bool RESID, bool BF16OUT, bool F32OUT>
__global__ __launch_bounds__(256) void gemm_mfma(
    const float* __restrict__ srcf, const unsigned short* __restrict__ srcb, int src_ld,
    const unsigned short* __restrict__ Wb,   // bf16 [ncols][64]
    const float* __restrict__ bias,
    float* __restrict__ dst, int dst_ld,
    unsigned short* __restrict__ dstb, int dstb_ld,
    const float* __restrict__ resid,
    const float* __restrict__ statsInSum, const float* __restrict__ statsInSq,
    const float* __restrict__ bnw, const float* __restrict__ bnb,
    float* __restrict__ statsOutSum, float* __restrict__ statsOutSq,
    float* __restrict__ zeroBuf, int zeroN) {
    __shared__ float cA[64], cB[64];
    __shared__ float sS[64], sQ[64];
    int tid = threadIdx.x;
    if (zeroBuf && blockIdx.x == 0 && blockIdx.y == 0 && tid < zeroN) zeroBuf[tid] = 0.f;
    int c0 = blockIdx.y * 64;

    if (BN_IN) {
        if (tid < 64) {
            float m = statsInSum[tid] / FN;
            float v = statsInSq[tid] / FN - m * m;
            float a = rsqrtf(v + BN_EPS) * bnw[tid];
            cA[tid] = a;
            cB[tid] = bnb[tid] - m * a;
        }
        __syncthreads();
    }

    int w = tid >> 6, lane = tid & 63;
    int n16 = lane & 15, quad = lane >> 4;

    // B fragments once per block
    bf16x8 bfr[4][2];
#pragma unroll
    for (int t = 0; t < 4; ++t) {
        int col = c0 + t * 16 + n16;
        const unsigned short* bsrc = Wb + (size_t)col * 64 + quad * 8;
#pragma unroll
        for (int kk = 0; kk < 2; ++kk)
            bfr[t][kk] = *(const bf16x8*)(bsrc + kk * 32);
    }

    float ls[4] = {0.f, 0.f, 0.f, 0.f}, lq[4] = {0.f, 0.f, 0.f, 0.f};
    constexpr int NT = (GN + 63) / 64;  // 1563
    for (int tile = blockIdx.x; tile < NT; tile += gridDim.x) {
        int r0 = tile * 64;
        int arow = r0 + w * 16 + n16;
        int arc = arow < GN ? arow : 0;

        bf16x8 afr[2];
        if (ABF16) {
            const unsigned short* asrc = srcb + (size_t)arc * src_ld + quad * 8;
#pragma unroll
            for (int kk = 0; kk < 2; ++kk)
                afr[kk] = *(const bf16x8*)(asrc + kk * 32);
        } else {
            const float* asrc = srcf + (size_t)arc * src_ld + quad * 8;
#pragma unroll
            for (int kk = 0; kk < 2; ++kk) {
                const float4* p = (const float4*)(asrc + kk * 32);
                float4 x0 = p[0], x1 = p[1];
                float av[8] = {x0.x, x0.y, x0.z, x0.w, x1.x, x1.y, x1.z, x1.w};
                if (BN_IN) {
                    int kb = quad * 8 + kk * 32;
#pragma unroll
                    for (int j = 0; j < 8; ++j) {
                        float t = av[j] * cA[kb + j] + cB[kb + j];
                        av[j] = fmaxf(t, 0.01f * t);
                    }
                }
                uint4 fu;
                fu.x = packbf2(av[0], av[1]); fu.y = packbf2(av[2], av[3]);
                fu.z = packbf2(av[4], av[5]); fu.w = packbf2(av[6], av[7]);
                afr[kk] = __builtin_bit_cast(bf16x8, fu);
            }
        }

        f32x4 acc[4] = {{0.f, 0.f, 0.f, 0.f}, {0.f, 0.f, 0.f, 0.f},
                        {0.f, 0.f, 0.f, 0.f}, {0.f, 0.f, 0.f, 0.f}};
#pragma unroll
        for (int t = 0; t < 4; ++t) {
            acc[t] = __builtin_amdgcn_mfma_f32_16x16x32_bf16(afr[0], bfr[t][0], acc[t], 0, 0, 0);
            acc[t] = __builtin_amdgcn_mfma_f32_16x16x32_bf16(afr[1], bfr[t][1], acc[t], 0, 0, 0);
        }

        // epilogue: D row = r0 + w*16 + quad*4 + r, col = c0 + t*16 + n16
#pragma unroll
        for (int t = 0; t < 4; ++t) {
            int col = c0 + t * 16 + n16;
            float bv = bias[col];
#pragma unroll
            for (int r = 0; r < 4; ++r) {
                int row = r0 + w * 16 + quad * 4 + r;
                if (row < GN) {
                    float o = acc[t][r] + bv;
                    if (RESID) o += resid[(size_t)row * dst_ld + col];
                    if (F32OUT) dst[(size_t)row * dst_ld + col] = o;
                    if (BF16OUT) dstb[(size_t)row * dstb_ld + col] = bf16rn(o);
                    if (STATS) { ls[t] += o; lq[t] += o * o; }
                }
            }
        }
    }

    if (STATS) {
        if (tid < 64) { sS[tid] = 0.f; sQ[tid] = 0.f; }
        __syncthreads();
#pragma unroll
        for (int t = 0; t < 4; ++t) {
            float s = ls[t], q = lq[t];
            s += __shfl_down(s, 16, 64); s += __shfl_down(s, 32, 64);
            q += __shfl_down(q, 16, 64); q += __shfl_down(q, 32, 64);
            if (lane < 16) {
                atomicAdd(&sS[t * 16 + n16], s);
                atomicAdd(&sQ[t * 16 + n16], q);
            }
        }
        __syncthreads();
        if (tid < 64) {
            atomicAdd(&statsOutSum[c0 + tid], sS[tid]);
            atomicAdd(&statsOutSq[c0 + tid], sQ[tid]);
        }
    }
}

// ---------------- classifier tail (bf16 y1) ----------------

__global__ __launch_bounds__(256) void cls2_kernel(
    const unsigned short* __restrict__ y1b,
    const float* __restrict__ sum, const float* __restrict__ sq,
    const float* __restrict__ bnw, const float* __restrict__ bnb,
    const float* __restrict__ w2, const float* __restrict__ b2,
    float* __restrict__ out) {
    int node = blockIdx.x * 4 + (threadIdx.x >> 6);
    int d = threadIdx.x & 63;
    if (node >= GN) return;
    float partial = 0.f;
#pragma unroll
    for (int hh = 0; hh < 2; ++hh) {
        int c = d + hh * 64;
        float m = sum[c] / FN;
        float var = sq[c] / FN - m * m;
        float a = rsqrtf(var + BN_EPS) * bnw[c];
        float v = bfu16(y1b[(size_t)node * 128 + c]);
        v = v * a + (bnb[c] - m * a);
        v = fmaxf(v, 0.01f * v);
        partial += v * w2[c];
    }
    for (int o = 32; o >= 1; o >>= 1) partial += __shfl_down(partial, o, 64);
    if (d == 0) out[node] = partial + b2[0];
}

// ---------------- launcher ----------------

extern "C" void kernel_launch(void* const* d_in, const int* in_sizes, int n_in,
                              void* d_out, int out_size, void* d_ws, size_t ws_size,
                              hipStream_t stream) {
    (void)in_sizes; (void)n_in; (void)out_size; (void)ws_size;
    const float* x    = (const float*)d_in[0];
    const int*   ei   = (const int*)d_in[1];
    const float* attr = (const float*)d_in[2];
    const float* bnpw = (const float*)d_in[3];
    const float* bnpb = (const float*)d_in[4];
    const float* elw  = (const float*)d_in[5];
    const float* elb  = (const float*)d_in[6];
    const float* l1w  = (const float*)d_in[7];
    const float* l1b  = (const float*)d_in[8];
    const float* bnmw = (const float*)d_in[9];
    const float* bnmb = (const float*)d_in[10];
    const float* l2w  = (const float*)d_in[11];
    const float* l2b  = (const float*)d_in[12];
    const float* epsA = (const float*)d_in[13];
    const float* c1w  = (const float*)d_in[14];
    const float* c1b  = (const float*)d_in[15];
    const float* cbw  = (const float*)d_in[16];
    const float* cbb  = (const float*)d_in[17];
    const float* c2w  = (const float*)d_in[18];
    const float* c2b  = (const float*)d_in[19];
    const int* srcArr = ei;
    const int* dstArr = ei + GE;

    char* base = (char*)d_ws;
    size_t ofs = 0;
    auto alloc = [&](size_t bytes) {
        void* p = base + ofs;
        ofs = (ofs + bytes + 1023) & ~(size_t)1023;
        return p;
    };
    int* off              = (int*)alloc((size_t)(GN + 1) * 4);
    int* cursor           = (int*)alloc((size_t)GN * 4);        // doubles as deg
    int* src_sorted       = (int*)alloc((size_t)GE * 4);
    unsigned* attr_sorted = (unsigned*)alloc((size_t)GE * 32);  // bf16 rows, 32B
    unsigned short* wbf   = (unsigned short*)alloc(40960 * 2);
    int* bsum   = (int*)alloc(1024);
    int* bbase  = (int*)alloc(1024);
    float* stP0 = (float*)alloc(512);
    float* stP1 = (float*)alloc(512);
    float* stM  = (float*)alloc(512);
    float* stC  = (float*)alloc(1024);
    float* h = (float*)alloc((size_t)GN * 256);
    float* z = (float*)alloc((size_t)GN * 256);
    unsigned short* zb = (unsigned short*)alloc((size_t)GN * 128);
    unsigned short* xb = (unsigned short*)alloc((size_t)GN * 128);
    unsigned short* hb = (unsigned short*)alloc((size_t)GN * 128);
    unsigned short* y1b = (unsigned short*)attr_sorted;  // reuse (25.6MB <= 51.2MB)

    constexpr int NB = (GN + 1023) / 1024;  // 98
    float* stP[2] = {stP0, stP1};

    // ---- CSR by dst + sorted materialization (bf16 attr) ----
    hipMemsetAsync(cursor, 0, (size_t)GN * 4, stream);
    hist_kernel<<<2048, 256, 0, stream>>>(dstArr, cursor);
    bsum_kernel<<<NB, 256, 0, stream>>>(cursor, bsum, l1w, l2w, c1w, wbf);
    bscan_kernel<<<1, 64, 0, stream>>>(bsum, bbase, off + GN, NB);
    bscatter_kernel<<<NB, 256, 0, stream>>>(cursor, bbase, off);
    fill_sorted_kernel<<<2048, 256, 0, stream>>>(srcArr, dstArr, (const float4*)attr,
                                                 cursor, src_sorted, attr_sorted, stP0);

    // ---- layer-0 pre-BN stats on x (+ x -> bf16) ----
    col_stats64<<<512, 256, 0, stream>>>(x, stP0, stP0 + 64, xb);

    const float* hsrc = x;
    const unsigned short* hbsrc = xb;
    dim3 gg(782, 1);
    for (int i = 0; i < 4; ++i) {
        float* sIn = stP[i & 1];
        float* sNext = stP[(i + 1) & 1];
        aggregate_kernel<<<25000, 256, 0, stream>>>(
            hsrc, hbsrc, sIn, sIn + 64, bnpw + i * 64, bnpb + i * 64, (i > 0) ? 1 : 0,
            off, src_sorted, attr_sorted, elw + i * 1024, elb + i * 64, epsA, i,
            zb, stM);
        // gemm1: z = zb @ l1w^T + b ; stats -> stM ; zero next stats buffer
        gemm_mfma<false, true, true, false, false, true><<<gg, 256, 0, stream>>>(
            nullptr, zb, 64, wbf + i * 4096, l1b + i * 64, z, 64, nullptr, 0, nullptr,
            nullptr, nullptr, nullptr, nullptr, stM, stM + 64,
            (i == 3) ? stC : sNext, (i == 3) ? 256 : 128);
        // gemm2: h = leaky(bn(z)) @ l2w^T + b [+h] ; stats -> sNext ; bf16 copy
        if (i == 0)
            gemm_mfma<true, false, true, false, true, true><<<gg, 256, 0, stream>>>(
                z, nullptr, 64, wbf + 16384 + i * 4096, l2b + i * 64, h, 64, hb, 64,
                nullptr, stM, stM + 64, bnmw + i * 64, bnmb + i * 64,
                sNext, sNext + 64, nullptr, 0);
        else if (i < 3)
            gemm_mfma<true, false, true, true, true, true><<<gg, 256, 0, stream>>>(
                z, nullptr, 64, wbf + 16384 + i * 4096, l2b + i * 64, h, 64, hb, 64,
                h, stM, stM + 64, bnmw + i * 64, bnmb + i * 64,
                sNext, sNext + 64, nullptr, 0);
        else
            gemm_mfma<true, false, false, true, true, true><<<gg, 256, 0, stream>>>(
                z, nullptr, 64, wbf + 16384 + i * 4096, l2b + i * 64, h, 64, hb, 64,
                h, stM, stM + 64, bnmw + i * 64, bnmb + i * 64,
                nullptr, nullptr, nullptr, 0);
        hsrc = h;
        hbsrc = hb;
    }

    // ---- classifier: y1b = hb @ c1w^T + b (bf16 out only), then BN+leaky+dot ----
    dim3 gc(391, 2);
    gemm_mfma<false, true, true, false, true, false><<<gc, 256, 0, stream>>>(
        nullptr, hb, 64, wbf + 32768, c1b, nullptr, 128, y1b, 128, nullptr,
        nullptr, nullptr, nullptr, nullptr, stC, stC + 128, nullptr, 0);
    cls2_kernel<<<25000, 256, 0, stream>>>(y1b, stC, stC + 128, cbw, cbb, c2w, c2b,
                                           (float*)d_out);
}